// Round 11
// baseline (200.422 us; speedup 1.0000x reference)
//
#include <hip/hip_runtime.h>
#include <hip/hip_bf16.h>

#define N_ROWS 8192
#define N_HALF 4096
#define DIM    2048
#define INV_T  2.0f   // 1/TEMP, TEMP=0.5
#define NBB    32     // 256-blocks per side
#define NTRI   528    // 32*33/2 pairs
#define NFULL  512    // full-tile blocks (triangle idx 0..511) = 2 clean rounds
#define NTAIL  128    // last 16 pairs M-split x8 (32-row sub-blocks)
#define NPH    64     // DIM / 32 K-phases

typedef __attribute__((ext_vector_type(8))) short bf16x8;
typedef __attribute__((ext_vector_type(4))) float f32x4;

__device__ __forceinline__ float bf2f(short s) {
  return __uint_as_float(((unsigned int)(unsigned short)s) << 16);
}

__device__ __forceinline__ short f2bf(float x) {
  unsigned int u = __float_as_uint(x);
  u += 0x7fffu + ((u >> 16) & 1u);
  return (short)(u >> 16);
}

__device__ __forceinline__ void gload_lds16(const void* g, void* l) {
  __builtin_amdgcn_global_load_lds(
      (const __attribute__((address_space(1))) unsigned int*)g,
      (__attribute__((address_space(3))) unsigned int*)l, 16, 0, 0);
}

// ---------------------------------------------------------------------------
// Kernel 1: fused normalize + positives + self-dots (round-9 verbatim).
// ---------------------------------------------------------------------------
__global__ __launch_bounds__(256) void normpos_k(
    const float* __restrict__ xi, const float* __restrict__ xj,
    short* __restrict__ z, float* __restrict__ pos,
    float* __restrict__ selfd)
{
  const int b = blockIdx.x;            // 0..4095
  const int t = threadIdx.x;
  const float4* si = (const float4*)(xi + (size_t)b * DIM);
  const float4* sj = (const float4*)(xj + (size_t)b * DIM);
  float4 a0 = si[t * 2], a1 = si[t * 2 + 1];
  float4 c0 = sj[t * 2], c1 = sj[t * 2 + 1];
  float ssi = a0.x*a0.x + a0.y*a0.y + a0.z*a0.z + a0.w*a0.w
            + a1.x*a1.x + a1.y*a1.y + a1.z*a1.z + a1.w*a1.w;
  float ssj = c0.x*c0.x + c0.y*c0.y + c0.z*c0.z + c0.w*c0.w
            + c1.x*c1.x + c1.y*c1.y + c1.z*c1.z + c1.w*c1.w;
  #pragma unroll
  for (int m = 1; m < 64; m <<= 1) {
    ssi += __shfl_xor(ssi, m, 64);
    ssj += __shfl_xor(ssj, m, 64);
  }
  __shared__ float ri[4], rj[4];
  if ((t & 63) == 0) { ri[t >> 6] = ssi; rj[t >> 6] = ssj; }
  __syncthreads();
  float sci = 1.0f / fmaxf(sqrtf(ri[0] + ri[1] + ri[2] + ri[3]), 1e-12f);
  float scj = 1.0f / fmaxf(sqrtf(rj[0] + rj[1] + rj[2] + rj[3]), 1e-12f);

  float fi[8] = {a0.x, a0.y, a0.z, a0.w, a1.x, a1.y, a1.z, a1.w};
  float fj[8] = {c0.x, c0.y, c0.z, c0.w, c1.x, c1.y, c1.z, c1.w};
  bf16x8 pi, pj;
  float dp = 0.f, dsi = 0.f, dsj = 0.f;
  #pragma unroll
  for (int e = 0; e < 8; ++e) {
    short qi = f2bf(fi[e] * sci), qj = f2bf(fj[e] * scj);
    pi[e] = qi; pj[e] = qj;
    float vi = bf2f(qi), vj = bf2f(qj);
    dp  += vi * vj;
    dsi += vi * vi;
    dsj += vj * vj;
  }
  *((bf16x8*)(z + (size_t)b * DIM) + t)            = pi;
  *((bf16x8*)(z + (size_t)(b + N_HALF) * DIM) + t) = pj;

  #pragma unroll
  for (int m = 1; m < 64; m <<= 1) {
    dp  += __shfl_xor(dp, m, 64);
    dsi += __shfl_xor(dsi, m, 64);
    dsj += __shfl_xor(dsj, m, 64);
  }
  __shared__ float rp[4], rsi[4], rsj[4];
  if ((t & 63) == 0) { rp[t >> 6] = dp; rsi[t >> 6] = dsi; rsj[t >> 6] = dsj; }
  __syncthreads();
  if (t == 0) {
    float p = rp[0] + rp[1] + rp[2] + rp[3];
    pos[b]           = p;
    pos[b + N_HALF]  = p;
    selfd[b]          = rsi[0] + rsi[1] + rsi[2] + rsi[3];
    selfd[b + N_HALF] = rsj[0] + rsj[1] + rsj[2] + rsj[3];
  }
}

// ---------------------------------------------------------------------------
// Kernel 2: symmetric fused sim-tile + exp row/col sums.  256x256 tiles
// (round-3 block internals — best measured per-block throughput) + clean
// grid (round-9 trick):
//  bids [0,512):  full 256x256 tiles = triangle idx 0..511 -> EXACTLY
//                 2 clean rounds at 1 block/CU (512 = 8*64, XCD-bijective).
//  bids [512,640): tail — triangle idx 512..527 (16 near-diagonal pairs)
//                 M-split x8 into 32-row x 256-col blocks (full K).
// Full path: 8 waves (2M x 4N), per-wave 128x64 (acc[8][4], 32 MFMA/phase).
// 4-slot LDS rotation lead-3 (A 16K + B 16K per slot = 128 KiB, 1 blk/CU).
// STAGE = 4 gload_lds16 (8 KB each); steady vmcnt(8), drain 4 -> 0
// (round-3 HW-verified ledger: wait forces STAGE(p), keeps p+1,p+2 in
// flight; barrier after wait makes it cross-wave safe).
// Swizzle (both sides, linear gload dest): LDS row q=r>>1 (128 B),
// 16B slot s = ((r&1)*4 + k4) ^ (q&7).
// Row-sums always; col-sums iff bi != bj (each unordered pair counted once;
// diagonal exp(self) subtracted in loss_k).
// ---------------------------------------------------------------------------
__global__ __launch_bounds__(512, 1) void simexp_k(
    const short* __restrict__ z, float* __restrict__ denom)
{
  __shared__ char lds[131072];
  char* ldsA = lds;            // 4 x 16384
  char* ldsB = lds + 65536;    // 4 x 16384

  const int t    = threadIdx.x;
  const int wave = t >> 6, lane = t & 63;
  const int bid  = blockIdx.x;

  // shared staging-source decomposition (swizzle-inverse of linear dest):
  // one 8 KiB call = 512 thr x 16B = LDS rows q=0..63 = logical rows 0..127.
  const int sq  = t >> 3;
  const int ss0 = (t & 7) ^ (sq & 7);
  const int sr  = 2 * sq + (ss0 >> 2);
  const int sk4 = ss0 & 3;

  if (bid < NFULL) {
    // ===================== FULL 256x256 TILE PATH ========================
    const int wr = wave >> 2, wc = wave & 3;   // 2M x 4N wave grid

    int idx = (bid & 7) * (NFULL / 8) + (bid >> 3);   // XCD-bijective
    int bi = 0;
    while (idx >= NBB - bi) { idx -= NBB - bi; ++bi; }
    const int bj   = bi + idx;
    const int row0 = bi * 256;
    const int col0 = bj * 256;

    const short* zA = z + (size_t)(row0 + sr) * DIM + sk4 * 8;
    const short* zB = z + (size_t)(col0 + sr) * DIM + sk4 * 8;
    char* dA = ldsA + wave * 1024;              // wave-uniform dest bases
    char* dB = ldsB + wave * 1024;

    int offA[8], offB[4];
    #pragma unroll
    for (int m = 0; m < 8; ++m) {
      int r = wr * 128 + m * 16 + (lane & 15);
      int q = r >> 1;
      int s = ((lane >> 4) + (r & 1) * 4) ^ (q & 7);
      offA[m] = q * 128 + s * 16;
    }
    #pragma unroll
    for (int n = 0; n < 4; ++n) {
      int r = wc * 64 + n * 16 + (lane & 15);
      int q = r >> 1;
      int s = ((lane >> 4) + (r & 1) * 4) ^ (q & 7);
      offB[n] = q * 128 + s * 16;
    }

    f32x4 acc[8][4] = {};

#define STAGE(kh, slot) do {                                   \
      const short* pa_ = zA + (kh) * 32;                       \
      const short* pb_ = zB + (kh) * 32;                       \
      char* da_ = dA + (slot) * 16384;                         \
      char* db_ = dB + (slot) * 16384;                         \
      gload_lds16(pa_,             da_);                       \
      gload_lds16(pa_ + 128 * DIM, da_ + 8192);                \
      gload_lds16(pb_,             db_);                       \
      gload_lds16(pb_ + 128 * DIM, db_ + 8192);                \
    } while (0)

    // prologue: lead-3
    STAGE(0, 0);
    STAGE(1, 1);
    STAGE(2, 2);

    for (int p = 0; p < NPH; ++p) {
      if (p < NPH - 2)       asm volatile("s_waitcnt vmcnt(8)" ::: "memory");
      else if (p == NPH - 2) asm volatile("s_waitcnt vmcnt(4)" ::: "memory");
      else                   asm volatile("s_waitcnt vmcnt(0)" ::: "memory");
      __builtin_amdgcn_s_barrier();
      __builtin_amdgcn_sched_barrier(0);

      const char* Ab = ldsA + (p & 3) * 16384;
      const char* Bb = ldsB + (p & 3) * 16384;
      bf16x8 a[8], b[4];
      #pragma unroll
      for (int m = 0; m < 8; ++m) a[m] = *(const bf16x8*)(Ab + offA[m]);
      #pragma unroll
      for (int n = 0; n < 4; ++n) b[n] = *(const bf16x8*)(Bb + offB[n]);

      if (p <= NPH - 4) STAGE(p + 3, (p + 3) & 3);  // slot (p-1)%4: its
                                                    // readers passed barrier p

      __builtin_amdgcn_s_setprio(1);
      #pragma unroll
      for (int m = 0; m < 8; ++m)
        #pragma unroll
        for (int n = 0; n < 4; ++n)
          acc[m][n] = __builtin_amdgcn_mfma_f32_16x16x32_bf16(a[m], b[n],
                                                              acc[m][n], 0, 0, 0);
      __builtin_amdgcn_s_setprio(0);
      __builtin_amdgcn_sched_barrier(0);
    }
#undef STAGE

    #pragma unroll
    for (int m = 0; m < 8; ++m)
      #pragma unroll
      for (int n = 0; n < 4; ++n)
        #pragma unroll
        for (int r = 0; r < 4; ++r)
          acc[m][n][r] = __expf(acc[m][n][r] * INV_T);

    // row sums: C layout col = lane&15, row = (lane>>4)*4 + reg
    #pragma unroll
    for (int m = 0; m < 8; ++m) {
      #pragma unroll
      for (int r = 0; r < 4; ++r) {
        float s = acc[m][0][r] + acc[m][1][r] + acc[m][2][r] + acc[m][3][r];
        s += __shfl_xor(s, 1, 64);
        s += __shfl_xor(s, 2, 64);
        s += __shfl_xor(s, 4, 64);
        s += __shfl_xor(s, 8, 64);
        if ((lane & 15) == 0) {
          int grow = row0 + wr * 128 + m * 16 + (lane >> 4) * 4 + r;
          atomicAdd(&denom[grow], s);
        }
      }
    }

    if (bi != bj) {
      #pragma unroll
      for (int n = 0; n < 4; ++n) {
        float cs = 0.f;
        #pragma unroll
        for (int m = 0; m < 8; ++m)
          #pragma unroll
          for (int r = 0; r < 4; ++r)
            cs += acc[m][n][r];
        cs += __shfl_xor(cs, 16, 64);
        cs += __shfl_xor(cs, 32, 64);
        if ((lane >> 4) == 0) {
          int gcol = col0 + wc * 64 + n * 16 + (lane & 15);
          atomicAdd(&denom[gcol], cs);
        }
      }
    }
  } else {
    // ===================== TAIL PATH: 32-row x 256-col ====================
    const int sub = bid - NFULL;               // 0..127
    int idx = NFULL + (sub >> 3);              // triangle idx 512..527
    int bi = 0;
    while (idx >= NBB - bi) { idx -= NBB - bi; ++bi; }
    const int bj   = bi + idx;
    const int row0 = bi * 256 + (sub & 7) * 32;
    const int col0 = bj * 256;

    const short* zB = z + (size_t)(col0 + sr) * DIM + sk4 * 8;
    // A staging: threads 0..127 (waves 0-1) cover the 32 rows (2 KiB)
    const int tA   = t & 127;
    const int sqA  = tA >> 3;                  // 0..15
    const int ss0A = (tA & 7) ^ (sqA & 7);
    const int srA  = 2 * sqA + (ss0A >> 2);    // 0..31
    const int sk4A = ss0A & 3;
    const short* zAs = z + (size_t)(row0 + srA) * DIM + sk4A * 8;
    char* dB = ldsB + wave * 1024;
    char* dA = ldsA + wave * 1024;             // waves 0,1 only -> 2 KiB

    int offA2[2], offB2[2];
    #pragma unroll
    for (int m = 0; m < 2; ++m) {
      int r = m * 16 + (lane & 15);            // 0..31
      int q = r >> 1;
      int s = ((lane >> 4) + (r & 1) * 4) ^ (q & 7);
      offA2[m] = q * 128 + s * 16;
    }
    #pragma unroll
    for (int n = 0; n < 2; ++n) {
      int r = wave * 32 + n * 16 + (lane & 15); // 0..255
      int q = r >> 1;
      int s = ((lane >> 4) + (r & 1) * 4) ^ (q & 7);
      offB2[n] = q * 128 + s * 16;
    }

    f32x4 acc2[2][2] = {};

#define STAGE_T(kh, slot) do {                                           \
      const short* pb_ = zB + (kh) * 32;                                 \
      char* db_ = dB + (slot) * 16384;                                   \
      gload_lds16(pb_,             db_);                                 \
      gload_lds16(pb_ + 128 * DIM, db_ + 8192);                          \
      if (wave < 2)                                                      \
        gload_lds16(zAs + (kh) * 32, ldsA + (slot) * 16384 + wave * 1024); \
    } while (0)

    STAGE_T(0, 0);
    STAGE_T(1, 1);
    STAGE_T(2, 2);

    for (int p = 0; p < NPH; ++p) {
      if (p < NPH - 2) {
        if (wave < 2) asm volatile("s_waitcnt vmcnt(6)" ::: "memory");
        else          asm volatile("s_waitcnt vmcnt(4)" ::: "memory");
      } else if (p == NPH - 2) {
        if (wave < 2) asm volatile("s_waitcnt vmcnt(3)" ::: "memory");
        else          asm volatile("s_waitcnt vmcnt(2)" ::: "memory");
      } else {
        asm volatile("s_waitcnt vmcnt(0)" ::: "memory");
      }
      __builtin_amdgcn_s_barrier();
      __builtin_amdgcn_sched_barrier(0);

      const char* Ab = ldsA + (p & 3) * 16384;
      const char* Bb = ldsB + (p & 3) * 16384;
      bf16x8 a0 = *(const bf16x8*)(Ab + offA2[0]);
      bf16x8 a1 = *(const bf16x8*)(Ab + offA2[1]);
      bf16x8 b0 = *(const bf16x8*)(Bb + offB2[0]);
      bf16x8 b1 = *(const bf16x8*)(Bb + offB2[1]);

      if (p <= NPH - 4) STAGE_T(p + 3, (p + 3) & 3);

      __builtin_amdgcn_s_setprio(1);
      acc2[0][0] = __builtin_amdgcn_mfma_f32_16x16x32_bf16(a0, b0, acc2[0][0], 0, 0, 0);
      acc2[0][1] = __builtin_amdgcn_mfma_f32_16x16x32_bf16(a0, b1, acc2[0][1], 0, 0, 0);
      acc2[1][0] = __builtin_amdgcn_mfma_f32_16x16x32_bf16(a1, b0, acc2[1][0], 0, 0, 0);
      acc2[1][1] = __builtin_amdgcn_mfma_f32_16x16x32_bf16(a1, b1, acc2[1][1], 0, 0, 0);
      __builtin_amdgcn_s_setprio(0);
      __builtin_amdgcn_sched_barrier(0);
    }
#undef STAGE_T

    #pragma unroll
    for (int m = 0; m < 2; ++m)
      #pragma unroll
      for (int n = 0; n < 2; ++n)
        #pragma unroll
        for (int r = 0; r < 4; ++r)
          acc2[m][n][r] = __expf(acc2[m][n][r] * INV_T);

    // row sums: each wave's 32-col slice, atomic-accumulated per row
    #pragma unroll
    for (int m = 0; m < 2; ++m) {
      #pragma unroll
      for (int r = 0; r < 4; ++r) {
        float s = acc2[m][0][r] + acc2[m][1][r];
        s += __shfl_xor(s, 1, 64);
        s += __shfl_xor(s, 2, 64);
        s += __shfl_xor(s, 4, 64);
        s += __shfl_xor(s, 8, 64);
        if ((lane & 15) == 0) {
          int grow = row0 + m * 16 + (lane >> 4) * 4 + r;
          atomicAdd(&denom[grow], s);
        }
      }
    }

    // col sums (partial over 32 rows, accumulated across the 8 M-splits)
    if (bi != bj) {
      #pragma unroll
      for (int n = 0; n < 2; ++n) {
        float cs = 0.f;
        #pragma unroll
        for (int m = 0; m < 2; ++m)
          #pragma unroll
          for (int r = 0; r < 4; ++r)
            cs += acc2[m][n][r];
        cs += __shfl_xor(cs, 16, 64);
        cs += __shfl_xor(cs, 32, 64);
        if ((lane >> 4) == 0) {
          int gcol = col0 + wave * 32 + n * 16 + (lane & 15);
          atomicAdd(&denom[gcol], cs);
        }
      }
    }
  }
}

// ---------------------------------------------------------------------------
// Kernel 3: loss = mean_i( log(denom_i - exp(self_i/T)) - pos_i/T )
// ---------------------------------------------------------------------------
__global__ __launch_bounds__(256) void loss_k(
    const float* __restrict__ denom, const float* __restrict__ pos,
    const float* __restrict__ selfd, float* __restrict__ out)
{
  const int t = threadIdx.x;
  float acc = 0.f;
  for (int i = t; i < N_ROWS; i += 256) {
    float d = denom[i] - __expf(selfd[i] * INV_T);
    acc += __logf(d) - pos[i] * INV_T;
  }
  #pragma unroll
  for (int m = 1; m < 64; m <<= 1) acc += __shfl_xor(acc, m, 64);
  __shared__ float red[4];
  if ((t & 63) == 0) red[t >> 6] = acc;
  __syncthreads();
  if (t == 0) out[0] = (red[0] + red[1] + red[2] + red[3]) / (float)N_ROWS;
}

// ---------------------------------------------------------------------------
extern "C" void kernel_launch(void* const* d_in, const int* in_sizes, int n_in,
                              void* d_out, int out_size, void* d_ws, size_t ws_size,
                              hipStream_t stream) {
  const float* xi = (const float*)d_in[0];
  const float* xj = (const float*)d_in[1];
  float* out = (float*)d_out;

  char*  ws    = (char*)d_ws;
  short* zb    = (short*)ws;                                   // 32 MiB bf16 z
  float* denom = (float*)(ws + (size_t)N_ROWS * DIM * 2);      // 8192 f32
  float* pos   = denom + N_ROWS;                               // 8192 f32
  float* selfd = pos + N_ROWS;                                 // 8192 f32

  hipMemsetAsync(denom, 0, N_ROWS * sizeof(float), stream);
  normpos_k<<<N_HALF, 256, 0, stream>>>(xi, xj, zb, pos, selfd);
  simexp_k<<<NFULL + NTAIL, 512, 0, stream>>>(zb, denom);
  loss_k<<<1, 256, 0, stream>>>(denom, pos, selfd, out);
}

// Round 13
// 200.232 us; speedup vs baseline: 1.0010x; 1.0010x over previous
//
#include <hip/hip_runtime.h>
#include <hip/hip_bf16.h>

#define N_ROWS 8192
#define N_HALF 4096
#define DIM    2048
#define INV_T  2.0f   // 1/TEMP, TEMP=0.5
#define NBB    32     // 256-blocks per side
#define NFULL  512    // full-tile blocks (triangle idx 0..511) = 2 clean rounds
#define NTAIL  128    // last 16 pairs M-split x8 (32-row sub-blocks)
#define NKT    32     // DIM / 64 K-tiles
#define NPH    64     // (tail path) DIM/32 phases

typedef __attribute__((ext_vector_type(8))) short bf16x8;
typedef __attribute__((ext_vector_type(4))) float f32x4;

__device__ __forceinline__ float bf2f(short s) {
  return __uint_as_float(((unsigned int)(unsigned short)s) << 16);
}

__device__ __forceinline__ short f2bf(float x) {
  unsigned int u = __float_as_uint(x);
  u += 0x7fffu + ((u >> 16) & 1u);
  return (short)(u >> 16);
}

__device__ __forceinline__ void gload_lds16(const void* g, void* l) {
  __builtin_amdgcn_global_load_lds(
      (const __attribute__((address_space(1))) unsigned int*)g,
      (__attribute__((address_space(3))) unsigned int*)l, 16, 0, 0);
}

// ---------------------------------------------------------------------------
// Kernel 1: fused normalize + positives + self-dots (verified, unchanged).
// ---------------------------------------------------------------------------
__global__ __launch_bounds__(256) void normpos_k(
    const float* __restrict__ xi, const float* __restrict__ xj,
    short* __restrict__ z, float* __restrict__ pos,
    float* __restrict__ selfd)
{
  const int b = blockIdx.x;            // 0..4095
  const int t = threadIdx.x;
  const float4* si = (const float4*)(xi + (size_t)b * DIM);
  const float4* sj = (const float4*)(xj + (size_t)b * DIM);
  float4 a0 = si[t * 2], a1 = si[t * 2 + 1];
  float4 c0 = sj[t * 2], c1 = sj[t * 2 + 1];
  float ssi = a0.x*a0.x + a0.y*a0.y + a0.z*a0.z + a0.w*a0.w
            + a1.x*a1.x + a1.y*a1.y + a1.z*a1.z + a1.w*a1.w;
  float ssj = c0.x*c0.x + c0.y*c0.y + c0.z*c0.z + c0.w*c0.w
            + c1.x*c1.x + c1.y*c1.y + c1.z*c1.z + c1.w*c1.w;
  #pragma unroll
  for (int m = 1; m < 64; m <<= 1) {
    ssi += __shfl_xor(ssi, m, 64);
    ssj += __shfl_xor(ssj, m, 64);
  }
  __shared__ float ri[4], rj[4];
  if ((t & 63) == 0) { ri[t >> 6] = ssi; rj[t >> 6] = ssj; }
  __syncthreads();
  float sci = 1.0f / fmaxf(sqrtf(ri[0] + ri[1] + ri[2] + ri[3]), 1e-12f);
  float scj = 1.0f / fmaxf(sqrtf(rj[0] + rj[1] + rj[2] + rj[3]), 1e-12f);

  float fi[8] = {a0.x, a0.y, a0.z, a0.w, a1.x, a1.y, a1.z, a1.w};
  float fj[8] = {c0.x, c0.y, c0.z, c0.w, c1.x, c1.y, c1.z, c1.w};
  bf16x8 pi, pj;
  float dp = 0.f, dsi = 0.f, dsj = 0.f;
  #pragma unroll
  for (int e = 0; e < 8; ++e) {
    short qi = f2bf(fi[e] * sci), qj = f2bf(fj[e] * scj);
    pi[e] = qi; pj[e] = qj;
    float vi = bf2f(qi), vj = bf2f(qj);
    dp  += vi * vj;
    dsi += vi * vi;
    dsj += vj * vj;
  }
  *((bf16x8*)(z + (size_t)b * DIM) + t)            = pi;
  *((bf16x8*)(z + (size_t)(b + N_HALF) * DIM) + t) = pj;

  #pragma unroll
  for (int m = 1; m < 64; m <<= 1) {
    dp  += __shfl_xor(dp, m, 64);
    dsi += __shfl_xor(dsi, m, 64);
    dsj += __shfl_xor(dsj, m, 64);
  }
  __shared__ float rp[4], rsi[4], rsj[4];
  if ((t & 63) == 0) { rp[t >> 6] = dp; rsi[t >> 6] = dsi; rsj[t >> 6] = dsj; }
  __syncthreads();
  if (t == 0) {
    float p = rp[0] + rp[1] + rp[2] + rp[3];
    pos[b]           = p;
    pos[b + N_HALF]  = p;
    selfd[b]          = rsi[0] + rsi[1] + rsi[2] + rsi[3];
    selfd[b + N_HALF] = rsj[0] + rsj[1] + rsj[2] + rsj[3];
  }
}

// ---------------------------------------------------------------------------
// Kernel 2: symmetric fused sim-tile + exp row/col sums.
//  bids [0,512):  full 256x256 tiles (triangle idx 0..511) — m201-style
//    4-sub-phase interleaved schedule, BK=64, dual 32 KiB buffers/matrix.
//  bids [512,640): tail — triangle idx 512..527 M-split x8 (32x256, full K),
//    r11-verified 4-slot rotation path, unchanged.
//
// Full path schedule per K-tile U (buffer u=U&1), 8 waves (2M x 4N),
// per-wave 128x64 (8m x 4n frags), K=64 = 2 k-slices:
//   sp0: read a_lo(k0) x4 + b(k0) x4 | stage B-h1(U+1) | bar | MFMA m0-3 k0 | bar
//   sp1: read a_hi(k0) x4            | stage A-h0(U+1) | bar | MFMA m4-7 k0 | bar
//   sp2: read a_lo(k1) x4 + b(k1) x4 | stage A-h1(U+1) | bar | MFMA m0-3 k1 | bar
//   sp3: read a_hi(k1) x4            | stage B-h0(U+2) | bar | MFMA m4-7 k1 |
//        vmcnt(2 / 0) | bar
// WAR ledger: region staged at sp_p was last READ (into regs, completed
// before that phase's MFMA) at sp_{p-1} or earlier; barriers order it.
// RAW ledger: tile U+1's 4 half-tiles are all older than the single stage
// issued after them (sp3's B-h0 of U+2) -> vmcnt(2) at sp3-end + barrier.
// LDS swizzle (BK=64): row r = 128 B; 16B chunk c stored at slot c ^ (r&7);
// staged via inverse-swizzled global source, linear gload dest.
// ---------------------------------------------------------------------------
__global__ __launch_bounds__(512, 1) void simexp_k(
    const short* __restrict__ z, float* __restrict__ denom)
{
  __shared__ char lds[131072];
  char* ldsA = lds;            // 2 buf x 32768
  char* ldsB = lds + 65536;    // 2 buf x 32768

  const int t    = threadIdx.x;
  const int wave = t >> 6, lane = t & 63;
  const int bid  = blockIdx.x;

  if (bid < NFULL) {
    // ===================== FULL 256x256, 4-SUB-PHASE PATH =================
    const int wr = wave >> 2, wc = wave & 3;   // 2M x 4N wave grid

    int idx = (bid & 7) * (NFULL / 8) + (bid >> 3);   // XCD-bijective
    int bi = 0;
    while (idx >= NBB - bi) { idx -= NBB - bi; ++bi; }
    const int bj   = bi + idx;
    const int row0 = bi * 256;
    const int col0 = bj * 256;

    // staging source (linear LDS dest, inverse-swizzled global source):
    // one 8 KiB call = 512 thr x 16B = 64 rows x 128 B.
    const int srow = t >> 3;                  // 0..63
    const int schk = (t & 7) ^ (srow & 7);    // k-chunk 0..7
    const short* srcA = z + (size_t)(row0 + srow) * DIM + schk * 8;
    const short* srcB = z + (size_t)(col0 + srow) * DIM + schk * 8;
    char* dA = ldsA + wave * 1024;
    char* dB = ldsB + wave * 1024;

#define STG_A(V, h) do {                                                      \
      gload_lds16(srcA + (size_t)((h)*128)    * DIM + (V)*64,                 \
                  dA + (((V)&1)<<15) + (h)*16384);                            \
      gload_lds16(srcA + (size_t)((h)*128+64) * DIM + (V)*64,                 \
                  dA + (((V)&1)<<15) + (h)*16384 + 8192);                     \
    } while (0)
#define STG_B(V, h) do {                                                      \
      gload_lds16(srcB + (size_t)((h)*128)    * DIM + (V)*64,                 \
                  dB + (((V)&1)<<15) + (h)*16384);                            \
      gload_lds16(srcB + (size_t)((h)*128+64) * DIM + (V)*64,                 \
                  dB + (((V)&1)<<15) + (h)*16384 + 8192);                     \
    } while (0)

    // ds_read byte offsets (swizzled): frag f, k-slice ks
    int offA[8][2], offB[4][2];
    #pragma unroll
    for (int f = 0; f < 8; ++f)
      #pragma unroll
      for (int ks = 0; ks < 2; ++ks) {
        int r = wr * 128 + f * 16 + (lane & 15);
        int c = ks * 4 + (lane >> 4);
        offA[f][ks] = r * 128 + ((c ^ (r & 7)) * 16);
      }
    #pragma unroll
    for (int f = 0; f < 4; ++f)
      #pragma unroll
      for (int ks = 0; ks < 2; ++ks) {
        int r = wc * 64 + f * 16 + (lane & 15);
        int c = ks * 4 + (lane >> 4);
        offB[f][ks] = r * 128 + ((c ^ (r & 7)) * 16);
      }

    f32x4 acc[8][4] = {};

    // prologue: tiles 0 and 1 fully staged (16 loads)
    STG_B(0, 0); STG_B(0, 1); STG_A(0, 0); STG_A(0, 1);
    STG_B(1, 0); STG_B(1, 1); STG_A(1, 0); STG_A(1, 1);
    asm volatile("s_waitcnt vmcnt(8)" ::: "memory");
    __builtin_amdgcn_s_barrier();

    for (int U = 0; U < NKT; ++U) {
      const char* Ab = ldsA + ((U & 1) << 15);
      const char* Bb = ldsB + ((U & 1) << 15);
      bf16x8 a[4], b[4];

      // ---------------- sp0: a_lo k0 + b k0 -> MFMA m0-3 k0 ----------------
      #pragma unroll
      for (int f = 0; f < 4; ++f) a[f] = *(const bf16x8*)(Ab + offA[f][0]);
      #pragma unroll
      for (int n = 0; n < 4; ++n) b[n] = *(const bf16x8*)(Bb + offB[n][0]);
      if (U >= 1 && U + 1 < NKT) STG_B(U + 1, 1);
      __builtin_amdgcn_sched_barrier(0);
      __builtin_amdgcn_s_barrier();
      __builtin_amdgcn_s_setprio(1);
      #pragma unroll
      for (int f = 0; f < 4; ++f)
        #pragma unroll
        for (int n = 0; n < 4; ++n)
          acc[f][n] = __builtin_amdgcn_mfma_f32_16x16x32_bf16(a[f], b[n],
                                                              acc[f][n], 0, 0, 0);
      __builtin_amdgcn_s_setprio(0);
      __builtin_amdgcn_sched_barrier(0);
      __builtin_amdgcn_s_barrier();

      // ---------------- sp1: a_hi k0 -> MFMA m4-7 k0 (b reused) ------------
      #pragma unroll
      for (int f = 0; f < 4; ++f) a[f] = *(const bf16x8*)(Ab + offA[4 + f][0]);
      if (U >= 1 && U + 1 < NKT) STG_A(U + 1, 0);
      __builtin_amdgcn_sched_barrier(0);
      __builtin_amdgcn_s_barrier();
      __builtin_amdgcn_s_setprio(1);
      #pragma unroll
      for (int f = 0; f < 4; ++f)
        #pragma unroll
        for (int n = 0; n < 4; ++n)
          acc[4 + f][n] = __builtin_amdgcn_mfma_f32_16x16x32_bf16(a[f], b[n],
                                                                  acc[4 + f][n], 0, 0, 0);
      __builtin_amdgcn_s_setprio(0);
      __builtin_amdgcn_sched_barrier(0);
      __builtin_amdgcn_s_barrier();

      // ---------------- sp2: a_lo k1 + b k1 -> MFMA m0-3 k1 ----------------
      #pragma unroll
      for (int f = 0; f < 4; ++f) a[f] = *(const bf16x8*)(Ab + offA[f][1]);
      #pragma unroll
      for (int n = 0; n < 4; ++n) b[n] = *(const bf16x8*)(Bb + offB[n][1]);
      if (U >= 1 && U + 1 < NKT) STG_A(U + 1, 1);
      __builtin_amdgcn_sched_barrier(0);
      __builtin_amdgcn_s_barrier();
      __builtin_amdgcn_s_setprio(1);
      #pragma unroll
      for (int f = 0; f < 4; ++f)
        #pragma unroll
        for (int n = 0; n < 4; ++n)
          acc[f][n] = __builtin_amdgcn_mfma_f32_16x16x32_bf16(a[f], b[n],
                                                              acc[f][n], 0, 0, 0);
      __builtin_amdgcn_s_setprio(0);
      __builtin_amdgcn_sched_barrier(0);
      __builtin_amdgcn_s_barrier();

      // ---------------- sp3: a_hi k1 -> MFMA m4-7 k1 -----------------------
      #pragma unroll
      for (int f = 0; f < 4; ++f) a[f] = *(const bf16x8*)(Ab + offA[4 + f][1]);
      if (U + 2 < NKT) STG_B(U + 2, 0);
      __builtin_amdgcn_sched_barrier(0);
      __builtin_amdgcn_s_barrier();
      __builtin_amdgcn_s_setprio(1);
      #pragma unroll
      for (int f = 0; f < 4; ++f)
        #pragma unroll
        for (int n = 0; n < 4; ++n)
          acc[4 + f][n] = __builtin_amdgcn_mfma_f32_16x16x32_bf16(a[f], b[n],
                                                                  acc[4 + f][n], 0, 0, 0);
      __builtin_amdgcn_s_setprio(0);
      __builtin_amdgcn_sched_barrier(0);
      // per-K-tile counted wait for tile U+1's half-tiles (RAW), then the
      // barrier makes it cross-wave (each wave stages 1/8 of every region).
      if (U < NKT - 2)       asm volatile("s_waitcnt vmcnt(2)" ::: "memory");
      else if (U == NKT - 2) asm volatile("s_waitcnt vmcnt(0)" ::: "memory");
      __builtin_amdgcn_s_barrier();
    }
#undef STG_A
#undef STG_B

    // ---- epilogue ----
    #pragma unroll
    for (int m = 0; m < 8; ++m)
      #pragma unroll
      for (int n = 0; n < 4; ++n)
        #pragma unroll
        for (int r = 0; r < 4; ++r)
          acc[m][n][r] = __expf(acc[m][n][r] * INV_T);

    // row sums: C layout col = lane&15, row = (lane>>4)*4 + reg
    #pragma unroll
    for (int m = 0; m < 8; ++m) {
      #pragma unroll
      for (int r = 0; r < 4; ++r) {
        float s = acc[m][0][r] + acc[m][1][r] + acc[m][2][r] + acc[m][3][r];
        s += __shfl_xor(s, 1, 64);
        s += __shfl_xor(s, 2, 64);
        s += __shfl_xor(s, 4, 64);
        s += __shfl_xor(s, 8, 64);
        if ((lane & 15) == 0) {
          int grow = row0 + wr * 128 + m * 16 + (lane >> 4) * 4 + r;
          atomicAdd(&denom[grow], s);
        }
      }
    }

    if (bi != bj) {
      #pragma unroll
      for (int n = 0; n < 4; ++n) {
        float cs = 0.f;
        #pragma unroll
        for (int m = 0; m < 8; ++m)
          #pragma unroll
          for (int r = 0; r < 4; ++r)
            cs += acc[m][n][r];
        cs += __shfl_xor(cs, 16, 64);
        cs += __shfl_xor(cs, 32, 64);
        if ((lane >> 4) == 0) {
          int gcol = col0 + wc * 64 + n * 16 + (lane & 15);
          atomicAdd(&denom[gcol], cs);
        }
      }
    }
  } else {
    // ===================== TAIL PATH (r11 verbatim): 32x256 ===============
    const int sub = bid - NFULL;               // 0..127
    int idx = NFULL + (sub >> 3);              // triangle idx 512..527
    int bi = 0;
    while (idx >= NBB - bi) { idx -= NBB - bi; ++bi; }
    const int bj   = bi + idx;
    const int row0 = bi * 256 + (sub & 7) * 32;
    const int col0 = bj * 256;

    const int sq  = t >> 3;
    const int ss0 = (t & 7) ^ (sq & 7);
    const int sr  = 2 * sq + (ss0 >> 2);
    const int sk4 = ss0 & 3;
    const short* zB = z + (size_t)(col0 + sr) * DIM + sk4 * 8;
    const int tA   = t & 127;
    const int sqA  = tA >> 3;                  // 0..15
    const int ss0A = (tA & 7) ^ (sqA & 7);
    const int srA  = 2 * sqA + (ss0A >> 2);    // 0..31
    const int sk4A = ss0A & 3;
    const short* zAs = z + (size_t)(row0 + srA) * DIM + sk4A * 8;
    char* dB = ldsB + wave * 1024;

    int offA2[2], offB2[2];
    #pragma unroll
    for (int m = 0; m < 2; ++m) {
      int r = m * 16 + (lane & 15);            // 0..31
      int q = r >> 1;
      int s = ((lane >> 4) + (r & 1) * 4) ^ (q & 7);
      offA2[m] = q * 128 + s * 16;
    }
    #pragma unroll
    for (int n = 0; n < 2; ++n) {
      int r = wave * 32 + n * 16 + (lane & 15); // 0..255
      int q = r >> 1;
      int s = ((lane >> 4) + (r & 1) * 4) ^ (q & 7);
      offB2[n] = q * 128 + s * 16;
    }

    f32x4 acc2[2][2] = {};

#define STAGE_T(kh, slot) do {                                           \
      const short* pb_ = zB + (kh) * 32;                                 \
      char* db_ = dB + (slot) * 16384;                                   \
      gload_lds16(pb_,             db_);                                 \
      gload_lds16(pb_ + 128 * DIM, db_ + 8192);                          \
      if (wave < 2)                                                      \
        gload_lds16(zAs + (kh) * 32, ldsA + (slot) * 16384 + wave * 1024); \
    } while (0)

    STAGE_T(0, 0);
    STAGE_T(1, 1);
    STAGE_T(2, 2);

    for (int p = 0; p < NPH; ++p) {
      if (p < NPH - 2) {
        if (wave < 2) asm volatile("s_waitcnt vmcnt(6)" ::: "memory");
        else          asm volatile("s_waitcnt vmcnt(4)" ::: "memory");
      } else if (p == NPH - 2) {
        if (wave < 2) asm volatile("s_waitcnt vmcnt(3)" ::: "memory");
        else          asm volatile("s_waitcnt vmcnt(2)" ::: "memory");
      } else {
        asm volatile("s_waitcnt vmcnt(0)" ::: "memory");
      }
      __builtin_amdgcn_s_barrier();
      __builtin_amdgcn_sched_barrier(0);

      const char* Ab = ldsA + (p & 3) * 16384;
      const char* Bb = ldsB + (p & 3) * 16384;
      bf16x8 a0 = *(const bf16x8*)(Ab + offA2[0]);
      bf16x8 a1 = *(const bf16x8*)(Ab + offA2[1]);
      bf16x8 b0 = *(const bf16x8*)(Bb + offB2[0]);
      bf16x8 b1 = *(const bf16x8*)(Bb + offB2[1]);

      if (p <= NPH - 4) STAGE_T(p + 3, (p + 3) & 3);

      __builtin_amdgcn_s_setprio(1);
      acc2[0][0] = __builtin_amdgcn_mfma_f32_16x16x32_bf16(a0, b0, acc2[0][0], 0, 0, 0);
      acc2[0][1] = __builtin_amdgcn_mfma_f32_16x16x32_bf16(a0, b1, acc2[0][1], 0, 0, 0);
      acc2[1][0] = __builtin_amdgcn_mfma_f32_16x16x32_bf16(a1, b0, acc2[1][0], 0, 0, 0);
      acc2[1][1] = __builtin_amdgcn_mfma_f32_16x16x32_bf16(a1, b1, acc2[1][1], 0, 0, 0);
      __builtin_amdgcn_s_setprio(0);
      __builtin_amdgcn_sched_barrier(0);
    }
#undef STAGE_T

    #pragma unroll
    for (int m = 0; m < 2; ++m)
      #pragma unroll
      for (int n = 0; n < 2; ++n)
        #pragma unroll
        for (int r = 0; r < 4; ++r)
          acc2[m][n][r] = __expf(acc2[m][n][r] * INV_T);

    #pragma unroll
    for (int m = 0; m < 2; ++m) {
      #pragma unroll
      for (int r = 0; r < 4; ++r) {
        float s = acc2[m][0][r] + acc2[m][1][r];
        s += __shfl_xor(s, 1, 64);
        s += __shfl_xor(s, 2, 64);
        s += __shfl_xor(s, 4, 64);
        s += __shfl_xor(s, 8, 64);
        if ((lane & 15) == 0) {
          int grow = row0 + m * 16 + (lane >> 4) * 4 + r;
          atomicAdd(&denom[grow], s);
        }
      }
    }

    if (bi != bj) {
      #pragma unroll
      for (int n = 0; n < 2; ++n) {
        float cs = 0.f;
        #pragma unroll
        for (int m = 0; m < 2; ++m)
          #pragma unroll
          for (int r = 0; r < 4; ++r)
            cs += acc2[m][n][r];
        cs += __shfl_xor(cs, 16, 64);
        cs += __shfl_xor(cs, 32, 64);
        if ((lane >> 4) == 0) {
          int gcol = col0 + wave * 32 + n * 16 + (lane & 15);
          atomicAdd(&denom[gcol], cs);
        }
      }
    }
  }
}

// ---------------------------------------------------------------------------
// Kernel 3: loss = mean_i( log(denom_i - exp(self_i/T)) - pos_i/T )
// ---------------------------------------------------------------------------
__global__ __launch_bounds__(256) void loss_k(
    const float* __restrict__ denom, const float* __restrict__ pos,
    const float* __restrict__ selfd, float* __restrict__ out)
{
  const int t = threadIdx.x;
  float acc = 0.f;
  for (int i = t; i < N_ROWS; i += 256) {
    float d = denom[i] - __expf(selfd[i] * INV_T);
    acc += __logf(d) - pos[i] * INV_T;
  }
  #pragma unroll
  for (int m = 1; m < 64; m <<= 1) acc += __shfl_xor(acc, m, 64);
  __shared__ float red[4];
  if ((t & 63) == 0) red[t >> 6] = acc;
  __syncthreads();
  if (t == 0) out[0] = (red[0] + red[1] + red[2] + red[3]) / (float)N_ROWS;
}

// ---------------------------------------------------------------------------
extern "C" void kernel_launch(void* const* d_in, const int* in_sizes, int n_in,
                              void* d_out, int out_size, void* d_ws, size_t ws_size,
                              hipStream_t stream) {
  const float* xi = (const float*)d_in[0];
  const float* xj = (const float*)d_in[1];
  float* out = (float*)d_out;

  char*  ws    = (char*)d_ws;
  short* zb    = (short*)ws;                                   // 32 MiB bf16 z
  float* denom = (float*)(ws + (size_t)N_ROWS * DIM * 2);      // 8192 f32
  float* pos   = denom + N_ROWS;                               // 8192 f32
  float* selfd = pos + N_ROWS;                                 // 8192 f32

  hipMemsetAsync(denom, 0, N_ROWS * sizeof(float), stream);
  normpos_k<<<N_HALF, 256, 0, stream>>>(xi, xj, zb, pos, selfd);
  simexp_k<<<NFULL + NTAIL, 512, 0, stream>>>(zb, denom);
  loss_k<<<1, 256, 0, stream>>>(denom, pos, selfd, out);
}

// Round 14
// 195.095 us; speedup vs baseline: 1.0273x; 1.0263x over previous
//
#include <hip/hip_runtime.h>
#include <hip/hip_bf16.h>

#define N_ROWS 8192
#define N_HALF 4096
#define DIM    2048
#define INV_T  2.0f   // 1/TEMP, TEMP=0.5
#define NBB    32     // 256-blocks per side
#define NFULL  512    // full-tile blocks (triangle idx 0..511) = 2 clean rounds
#define NTAIL  128    // last 16 pairs M-split x8 (32-row sub-blocks)
#define NKT    32     // DIM / 64 K-tiles
#define NPH    64     // (tail path) DIM/32 phases

typedef __attribute__((ext_vector_type(8))) short bf16x8;
typedef __attribute__((ext_vector_type(4))) float f32x4;

__device__ __forceinline__ float bf2f(short s) {
  return __uint_as_float(((unsigned int)(unsigned short)s) << 16);
}

__device__ __forceinline__ short f2bf(float x) {
  unsigned int u = __float_as_uint(x);
  u += 0x7fffu + ((u >> 16) & 1u);
  return (short)(u >> 16);
}

__device__ __forceinline__ void gload_lds16(const void* g, void* l) {
  __builtin_amdgcn_global_load_lds(
      (const __attribute__((address_space(1))) unsigned int*)g,
      (__attribute__((address_space(3))) unsigned int*)l, 16, 0, 0);
}

// ---------------------------------------------------------------------------
// Kernel 1: fused normalize + positives + self-dots + denom zero-init.
// ---------------------------------------------------------------------------
__global__ __launch_bounds__(256) void normpos_k(
    const float* __restrict__ xi, const float* __restrict__ xj,
    short* __restrict__ z, float* __restrict__ pos,
    float* __restrict__ selfd, float* __restrict__ denom)
{
  const int b = blockIdx.x;            // 0..4095
  const int t = threadIdx.x;
  const float4* si = (const float4*)(xi + (size_t)b * DIM);
  const float4* sj = (const float4*)(xj + (size_t)b * DIM);
  float4 a0 = si[t * 2], a1 = si[t * 2 + 1];
  float4 c0 = sj[t * 2], c1 = sj[t * 2 + 1];
  float ssi = a0.x*a0.x + a0.y*a0.y + a0.z*a0.z + a0.w*a0.w
            + a1.x*a1.x + a1.y*a1.y + a1.z*a1.z + a1.w*a1.w;
  float ssj = c0.x*c0.x + c0.y*c0.y + c0.z*c0.z + c0.w*c0.w
            + c1.x*c1.x + c1.y*c1.y + c1.z*c1.z + c1.w*c1.w;
  #pragma unroll
  for (int m = 1; m < 64; m <<= 1) {
    ssi += __shfl_xor(ssi, m, 64);
    ssj += __shfl_xor(ssj, m, 64);
  }
  __shared__ float ri[4], rj[4];
  if ((t & 63) == 0) { ri[t >> 6] = ssi; rj[t >> 6] = ssj; }
  __syncthreads();
  float sci = 1.0f / fmaxf(sqrtf(ri[0] + ri[1] + ri[2] + ri[3]), 1e-12f);
  float scj = 1.0f / fmaxf(sqrtf(rj[0] + rj[1] + rj[2] + rj[3]), 1e-12f);

  float fi[8] = {a0.x, a0.y, a0.z, a0.w, a1.x, a1.y, a1.z, a1.w};
  float fj[8] = {c0.x, c0.y, c0.z, c0.w, c1.x, c1.y, c1.z, c1.w};
  bf16x8 pi, pj;
  float dp = 0.f, dsi = 0.f, dsj = 0.f;
  #pragma unroll
  for (int e = 0; e < 8; ++e) {
    short qi = f2bf(fi[e] * sci), qj = f2bf(fj[e] * scj);
    pi[e] = qi; pj[e] = qj;
    float vi = bf2f(qi), vj = bf2f(qj);
    dp  += vi * vj;
    dsi += vi * vi;
    dsj += vj * vj;
  }
  *((bf16x8*)(z + (size_t)b * DIM) + t)            = pi;
  *((bf16x8*)(z + (size_t)(b + N_HALF) * DIM) + t) = pj;

  #pragma unroll
  for (int m = 1; m < 64; m <<= 1) {
    dp  += __shfl_xor(dp, m, 64);
    dsi += __shfl_xor(dsi, m, 64);
    dsj += __shfl_xor(dsj, m, 64);
  }
  __shared__ float rp[4], rsi[4], rsj[4];
  if ((t & 63) == 0) { rp[t >> 6] = dp; rsi[t >> 6] = dsi; rsj[t >> 6] = dsj; }
  __syncthreads();
  if (t == 0) {
    float p = rp[0] + rp[1] + rp[2] + rp[3];
    pos[b]           = p;
    pos[b + N_HALF]  = p;
    selfd[b]          = rsi[0] + rsi[1] + rsi[2] + rsi[3];
    selfd[b + N_HALF] = rsj[0] + rsj[1] + rsj[2] + rsj[3];
    denom[b]          = 0.f;
    denom[b + N_HALF] = 0.f;
  }
}

// ---------------------------------------------------------------------------
// Kernel 2: symmetric fused sim-tile + exp row/col sums.
//  bids [0,512): full 256x256 tiles — deep-stagger 2-phase schedule:
//    BK=64, 2 dbuf; LDS quarter-granular regions:
//      A-L = rows {0-63, 128-191} (each wave's frag0-3 rows), A-H = rest;
//      B-L = cols {0-63, 128-191}, B-H = rest.  Region = 16 KiB.
//    Per tile T (buf = T&1), phases:
//      ph1: read A-L frags + ALL B frags (B regs persist) | stage
//           {A-H,B-L,B-H}(T+1) | bar | lgkm0 | 32 MFMA (f0-3)
//      ph2: read A-H frags | stage A-L(T+2) | bar | lgkm0 |
//           32 MFMA (f4-7) | vmcnt(2) | bar
//    Ledger: WAR — A-L(T) last LDS-read in ph1 -> A-L(T+2) staged ph2(T)
//    writes buf[T&1] after that; {A-H,B,B}(T-1) last read ph1/ph2(T-1),
//    freed by that phase's lgkm+bar before ph1(T) stages into buf[(T+1)&1].
//    RAW — vmcnt(2) at ph2(T) end forces the 3 halves staged ph1(T) (2
//    phases ~1200cyc old) landed before ph1(T+1) reads them; leaves only
//    A-L(T+2) in flight.  Prologue: T0 all + T1 A-L (10 loads), vmcnt(2).
//    T=30: vmcnt(0).  Swizzle: LDS row=tile row (128 B), 16B chunk c at
//    slot c^(r&7); inverse-swizzled global source, linear gload dest.
//  bids [512,640): tail — r11/r13-verified 4-slot path (verbatim).
// ---------------------------------------------------------------------------
__global__ __launch_bounds__(512, 1) void simexp_k(
    const short* __restrict__ z, float* __restrict__ denom)
{
  __shared__ char lds[131072];
  char* ldsA = lds;            // 2 buf x 2 region x 16 KiB
  char* ldsB = lds + 65536;

  const int t    = threadIdx.x;
  const int wave = t >> 6, lane = t & 63;
  const int bid  = blockIdx.x;

  if (bid < NFULL) {
    // ===================== FULL 256x256 DEEP-STAGGER PATH =================
    const int wr = wave >> 2, wc = wave & 3;   // 2M x 4N wave grid

    int idx = (bid & 7) * (NFULL / 8) + (bid >> 3);   // XCD-bijective
    int bi = 0;
    while (idx >= NBB - bi) { idx -= NBB - bi; ++bi; }
    const int bj   = bi + idx;
    const int row0 = bi * 256;
    const int col0 = bj * 256;

    // staging source (linear dest, inverse-swizzled source):
    // one 8 KiB call = 512 thr x 16B = 64 rows x 128 B.
    const int srow = t >> 3;                  // 0..63
    const int schk = (t & 7) ^ (srow & 7);    // k-chunk 0..7
    const short* srcA = z + (size_t)(row0 + srow) * DIM + schk * 8;
    const short* srcB = z + (size_t)(col0 + srow) * DIM + schk * 8;

#define DSTA(T, half, grp) (ldsA + (((T)&1)<<15) + (half)*16384 + (grp)*8192 + wave*1024)
#define DSTB(T, half, grp) (ldsB + (((T)&1)<<15) + (half)*16384 + (grp)*8192 + wave*1024)
#define STG_A(T, half) do {                                                   \
      gload_lds16(srcA + (size_t)((half) ?  64 :   0) * DIM + (T)*64,         \
                  DSTA(T, half, 0));                                          \
      gload_lds16(srcA + (size_t)((half) ? 192 : 128) * DIM + (T)*64,         \
                  DSTA(T, half, 1));                                          \
    } while (0)
#define STG_B(T, half) do {                                                   \
      gload_lds16(srcB + (size_t)((half) ?  64 :   0) * DIM + (T)*64,         \
                  DSTB(T, half, 0));                                          \
      gload_lds16(srcB + (size_t)((half) ? 192 : 128) * DIM + (T)*64,         \
                  DSTB(T, half, 1));                                          \
    } while (0)

    // ds_read byte offsets (swizzled, region-relative to buffer base)
    int offA[8][2], offB[4][2];
    #pragma unroll
    for (int f = 0; f < 8; ++f)
      #pragma unroll
      for (int ks = 0; ks < 2; ++ks) {
        int r    = wr * 128 + f * 16 + (lane & 15);
        int half = (r >> 6) & 1;
        int lr   = (r & 63) + ((r >> 7) << 6);
        offA[f][ks] = half * 16384 + lr * 128
                    + ((((ks * 4) + (lane >> 4)) ^ (r & 7)) << 4);
      }
    #pragma unroll
    for (int n = 0; n < 4; ++n)
      #pragma unroll
      for (int ks = 0; ks < 2; ++ks) {
        int r    = wc * 64 + n * 16 + (lane & 15);
        int half = (r >> 6) & 1;
        int lr   = (r & 63) + ((r >> 7) << 6);
        offB[n][ks] = half * 16384 + lr * 128
                    + ((((ks * 4) + (lane >> 4)) ^ (r & 7)) << 4);
      }

    f32x4 acc[8][4] = {};
    bf16x8 acur[4][2], bfr[4][2];

    // prologue: T0 fully + T1's A-L (10 loads); T0 forced before entry
    STG_A(0, 0); STG_A(0, 1); STG_B(0, 0); STG_B(0, 1);
    STG_A(1, 0);
    asm volatile("s_waitcnt vmcnt(2)" ::: "memory");
    __builtin_amdgcn_s_barrier();

#define TILE(T, BOFF) do {                                                    \
      const char* Ab = ldsA + (BOFF);                                         \
      const char* Bb = ldsB + (BOFF);                                         \
      /* ---- ph1: A-L + all B reads | stage 3 halves(T+1) | 32 MFMA ---- */  \
      _Pragma("unroll")                                                       \
      for (int f = 0; f < 4; ++f) {                                           \
        acur[f][0] = *(const bf16x8*)(Ab + offA[f][0]);                       \
        acur[f][1] = *(const bf16x8*)(Ab + offA[f][1]);                       \
      }                                                                       \
      _Pragma("unroll")                                                       \
      for (int n = 0; n < 4; ++n) {                                           \
        bfr[n][0] = *(const bf16x8*)(Bb + offB[n][0]);                        \
        bfr[n][1] = *(const bf16x8*)(Bb + offB[n][1]);                        \
      }                                                                       \
      if ((T) <= 30) { STG_A((T)+1, 1); STG_B((T)+1, 0); STG_B((T)+1, 1); }   \
      __builtin_amdgcn_sched_barrier(0);                                      \
      __builtin_amdgcn_s_barrier();                                           \
      asm volatile("s_waitcnt lgkmcnt(0)" ::: "memory");                      \
      __builtin_amdgcn_sched_barrier(0);                                      \
      __builtin_amdgcn_s_setprio(1);                                          \
      _Pragma("unroll")                                                       \
      for (int ks = 0; ks < 2; ++ks)                                          \
        _Pragma("unroll")                                                     \
        for (int f = 0; f < 4; ++f)                                           \
          _Pragma("unroll")                                                   \
          for (int n = 0; n < 4; ++n)                                         \
            acc[f][n] = __builtin_amdgcn_mfma_f32_16x16x32_bf16(              \
                acur[f][ks], bfr[n][ks], acc[f][n], 0, 0, 0);                 \
      __builtin_amdgcn_s_setprio(0);                                          \
      __builtin_amdgcn_sched_barrier(0);                                      \
      __builtin_amdgcn_s_barrier();                                           \
      /* ---- ph2: A-H reads | stage A-L(T+2) | 32 MFMA | vmcnt ---- */       \
      _Pragma("unroll")                                                       \
      for (int f = 0; f < 4; ++f) {                                           \
        acur[f][0] = *(const bf16x8*)(Ab + offA[4 + f][0]);                   \
        acur[f][1] = *(const bf16x8*)(Ab + offA[4 + f][1]);                   \
      }                                                                       \
      if ((T) <= 29) STG_A((T)+2, 0);                                         \
      __builtin_amdgcn_sched_barrier(0);                                      \
      __builtin_amdgcn_s_barrier();                                           \
      asm volatile("s_waitcnt lgkmcnt(0)" ::: "memory");                      \
      __builtin_amdgcn_sched_barrier(0);                                      \
      __builtin_amdgcn_s_setprio(1);                                          \
      _Pragma("unroll")                                                       \
      for (int ks = 0; ks < 2; ++ks)                                          \
        _Pragma("unroll")                                                     \
        for (int f = 0; f < 4; ++f)                                           \
          _Pragma("unroll")                                                   \
          for (int n = 0; n < 4; ++n)                                         \
            acc[4 + f][n] = __builtin_amdgcn_mfma_f32_16x16x32_bf16(          \
                acur[f][ks], bfr[n][ks], acc[4 + f][n], 0, 0, 0);             \
      __builtin_amdgcn_s_setprio(0);                                          \
      __builtin_amdgcn_sched_barrier(0);                                      \
      if ((T) < 30)       asm volatile("s_waitcnt vmcnt(2)" ::: "memory");    \
      else if ((T) == 30) asm volatile("s_waitcnt vmcnt(0)" ::: "memory");    \
      __builtin_amdgcn_s_barrier();                                           \
    } while (0)

    for (int it = 0; it < NKT / 2; ++it) {
      TILE(2 * it,     0);
      TILE(2 * it + 1, 32768);
    }
#undef TILE
#undef STG_A
#undef STG_B
#undef DSTA
#undef DSTB

    // ---- epilogue ----
    #pragma unroll
    for (int m = 0; m < 8; ++m)
      #pragma unroll
      for (int n = 0; n < 4; ++n)
        #pragma unroll
        for (int r = 0; r < 4; ++r)
          acc[m][n][r] = __expf(acc[m][n][r] * INV_T);

    // row sums: C layout col = lane&15, row = (lane>>4)*4 + reg
    #pragma unroll
    for (int m = 0; m < 8; ++m) {
      #pragma unroll
      for (int r = 0; r < 4; ++r) {
        float s = acc[m][0][r] + acc[m][1][r] + acc[m][2][r] + acc[m][3][r];
        s += __shfl_xor(s, 1, 64);
        s += __shfl_xor(s, 2, 64);
        s += __shfl_xor(s, 4, 64);
        s += __shfl_xor(s, 8, 64);
        if ((lane & 15) == 0) {
          int grow = row0 + wr * 128 + m * 16 + (lane >> 4) * 4 + r;
          atomicAdd(&denom[grow], s);
        }
      }
    }

    if (bi != bj) {
      #pragma unroll
      for (int n = 0; n < 4; ++n) {
        float cs = 0.f;
        #pragma unroll
        for (int m = 0; m < 8; ++m)
          #pragma unroll
          for (int r = 0; r < 4; ++r)
            cs += acc[m][n][r];
        cs += __shfl_xor(cs, 16, 64);
        cs += __shfl_xor(cs, 32, 64);
        if ((lane >> 4) == 0) {
          int gcol = col0 + wc * 64 + n * 16 + (lane & 15);
          atomicAdd(&denom[gcol], cs);
        }
      }
    }
  } else {
    // ===================== TAIL PATH (r11 verbatim): 32x256 ===============
    const int sub = bid - NFULL;               // 0..127
    int idx = NFULL + (sub >> 3);              // triangle idx 512..527
    int bi = 0;
    while (idx >= NBB - bi) { idx -= NBB - bi; ++bi; }
    const int bj   = bi + idx;
    const int row0 = bi * 256 + (sub & 7) * 32;
    const int col0 = bj * 256;

    const int sq  = t >> 3;
    const int ss0 = (t & 7) ^ (sq & 7);
    const int sr  = 2 * sq + (ss0 >> 2);
    const int sk4 = ss0 & 3;
    const short* zB = z + (size_t)(col0 + sr) * DIM + sk4 * 8;
    const int tA   = t & 127;
    const int sqA  = tA >> 3;                  // 0..15
    const int ss0A = (tA & 7) ^ (sqA & 7);
    const int srA  = 2 * sqA + (ss0A >> 2);    // 0..31
    const int sk4A = ss0A & 3;
    const short* zAs = z + (size_t)(row0 + srA) * DIM + sk4A * 8;
    char* dB = ldsB + wave * 1024;

    int offA2[2], offB2[2];
    #pragma unroll
    for (int m = 0; m < 2; ++m) {
      int r = m * 16 + (lane & 15);            // 0..31
      int q = r >> 1;
      int s = ((lane >> 4) + (r & 1) * 4) ^ (q & 7);
      offA2[m] = q * 128 + s * 16;
    }
    #pragma unroll
    for (int n = 0; n < 2; ++n) {
      int r = wave * 32 + n * 16 + (lane & 15); // 0..255
      int q = r >> 1;
      int s = ((lane >> 4) + (r & 1) * 4) ^ (q & 7);
      offB2[n] = q * 128 + s * 16;
    }

    f32x4 acc2[2][2] = {};

#define STAGE_T(kh, slot) do {                                           \
      const short* pb_ = zB + (kh) * 32;                                 \
      char* db_ = dB + (slot) * 16384;                                   \
      gload_lds16(pb_,             db_);                                 \
      gload_lds16(pb_ + 128 * DIM, db_ + 8192);                          \
      if (wave < 2)                                                      \
        gload_lds16(zAs + (kh) * 32, ldsA + (slot) * 16384 + wave * 1024); \
    } while (0)

    STAGE_T(0, 0);
    STAGE_T(1, 1);
    STAGE_T(2, 2);

    for (int p = 0; p < NPH; ++p) {
      if (p < NPH - 2) {
        if (wave < 2) asm volatile("s_waitcnt vmcnt(6)" ::: "memory");
        else          asm volatile("s_waitcnt vmcnt(4)" ::: "memory");
      } else if (p == NPH - 2) {
        if (wave < 2) asm volatile("s_waitcnt vmcnt(3)" ::: "memory");
        else          asm volatile("s_waitcnt vmcnt(2)" ::: "memory");
      } else {
        asm volatile("s_waitcnt vmcnt(0)" ::: "memory");
      }
      __builtin_amdgcn_s_barrier();
      __builtin_amdgcn_sched_barrier(0);

      const char* Ab = ldsA + (p & 3) * 16384;
      const char* Bb = ldsB + (p & 3) * 16384;
      bf16x8 a0 = *(const bf16x8*)(Ab + offA2[0]);
      bf16x8 a1 = *(const bf16x8*)(Ab + offA2[1]);
      bf16x8 b0 = *(const bf16x8*)(Bb + offB2[0]);
      bf16x8 b1 = *(const bf16x8*)(Bb + offB2[1]);

      if (p <= NPH - 4) STAGE_T(p + 3, (p + 3) & 3);

      __builtin_amdgcn_s_setprio(1);
      acc2[0][0] = __builtin_amdgcn_mfma_f32_16x16x32_bf16(a0, b0, acc2[0][0], 0, 0, 0);
      acc2[0][1] = __builtin_amdgcn_mfma_f32_16x16x32_bf16(a0, b1, acc2[0][1], 0, 0, 0);
      acc2[1][0] = __builtin_amdgcn_mfma_f32_16x16x32_bf16(a1, b0, acc2[1][0], 0, 0, 0);
      acc2[1][1] = __builtin_amdgcn_mfma_f32_16x16x32_bf16(a1, b1, acc2[1][1], 0, 0, 0);
      __builtin_amdgcn_s_setprio(0);
      __builtin_amdgcn_sched_barrier(0);
    }
#undef STAGE_T

    #pragma unroll
    for (int m = 0; m < 2; ++m)
      #pragma unroll
      for (int n = 0; n < 2; ++n)
        #pragma unroll
        for (int r = 0; r < 4; ++r)
          acc2[m][n][r] = __expf(acc2[m][n][r] * INV_T);

    #pragma unroll
    for (int m = 0; m < 2; ++m) {
      #pragma unroll
      for (int r = 0; r < 4; ++r) {
        float s = acc2[m][0][r] + acc2[m][1][r];
        s += __shfl_xor(s, 1, 64);
        s += __shfl_xor(s, 2, 64);
        s += __shfl_xor(s, 4, 64);
        s += __shfl_xor(s, 8, 64);
        if ((lane & 15) == 0) {
          int grow = row0 + m * 16 + (lane >> 4) * 4 + r;
          atomicAdd(&denom[grow], s);
        }
      }
    }

    if (bi != bj) {
      #pragma unroll
      for (int n = 0; n < 2; ++n) {
        float cs = 0.f;
        #pragma unroll
        for (int m = 0; m < 2; ++m)
          #pragma unroll
          for (int r = 0; r < 4; ++r)
            cs += acc2[m][n][r];
        cs += __shfl_xor(cs, 16, 64);
        cs += __shfl_xor(cs, 32, 64);
        if ((lane >> 4) == 0) {
          int gcol = col0 + wave * 32 + n * 16 + (lane & 15);
          atomicAdd(&denom[gcol], cs);
        }
      }
    }
  }
}

// ---------------------------------------------------------------------------
// Kernel 3: loss = mean_i( log(denom_i - exp(self_i/T)) - pos_i/T )
// ---------------------------------------------------------------------------
__global__ __launch_bounds__(256) void loss_k(
    const float* __restrict__ denom, const float* __restrict__ pos,
    const float* __restrict__ selfd, float* __restrict__ out)
{
  const int t = threadIdx.x;
  float acc = 0.f;
  for (int i = t; i < N_ROWS; i += 256) {
    float d = denom[i] - __expf(selfd[i] * INV_T);
    acc += __logf(d) - pos[i] * INV_T;
  }
  #pragma unroll
  for (int m = 1; m < 64; m <<= 1) acc += __shfl_xor(acc, m, 64);
  __shared__ float red[4];
  if ((t & 63) == 0) red[t >> 6] = acc;
  __syncthreads();
  if (t == 0) out[0] = (red[0] + red[1] + red[2] + red[3]) / (float)N_ROWS;
}

// ---------------------------------------------------------------------------
extern "C" void kernel_launch(void* const* d_in, const int* in_sizes, int n_in,
                              void* d_out, int out_size, void* d_ws, size_t ws_size,
                              hipStream_t stream) {
  const float* xi = (const float*)d_in[0];
  const float* xj = (const float*)d_in[1];
  float* out = (float*)d_out;

  char*  ws    = (char*)d_ws;
  short* zb    = (short*)ws;                                   // 32 MiB bf16 z
  float* denom = (float*)(ws + (size_t)N_ROWS * DIM * 2);      // 8192 f32
  float* pos   = denom + N_ROWS;                               // 8192 f32
  float* selfd = pos + N_ROWS;                                 // 8192 f32

  normpos_k<<<N_HALF, 256, 0, stream>>>(xi, xj, zb, pos, selfd, denom);
  simexp_k<<<NFULL + NTAIL, 512, 0, stream>>>(zb, denom);
  loss_k<<<1, 256, 0, stream>>>(denom, pos, selfd, out);
}

// Round 16
// 150.563 us; speedup vs baseline: 1.3312x; 1.2958x over previous
//
#include <hip/hip_runtime.h>
#include <hip/hip_bf16.h>

#define N_ROWS 8192
#define N_HALF 4096
#define DIM    2048
#define ROWB   2048       // bytes per z row (fp8)
#define INV_T  2.0f
#define QSCL   64.0f      // z scaled by 64 before fp8 quant
#define SIMSCL 0.00048828125f  // INV_T / (QSCL*QSCL) = 2/4096
#define NG1    1024       // full tiles: sum_{bi}(63-2*bi), bj in [2bi,63)
#define NG2    256        // tail: 32 bj=63 tiles M-split x8
#define NPH    64         // DIM/32 K-phases

typedef __attribute__((ext_vector_type(4))) float f32x4;

__device__ __forceinline__ void gload_lds16(const void* g, void* l) {
  __builtin_amdgcn_global_load_lds(
      (const __attribute__((address_space(1))) unsigned int*)g,
      (__attribute__((address_space(3))) unsigned int*)l, 16, 0, 0);
}

// ---------------------------------------------------------------------------
// Kernel 1: fused normalize + fp8-quantize + positives + self-dots + denom=0.
// pos from fp32 normalized values (ref semantics); selfd from DECODED fp8
// (consistent with the MFMA diagonal, raw scale: sum of (64 z)^2).
// ---------------------------------------------------------------------------
__global__ __launch_bounds__(256) void normpos_k(
    const float* __restrict__ xi, const float* __restrict__ xj,
    char* __restrict__ zq, float* __restrict__ pos,
    float* __restrict__ selfd, float* __restrict__ denom)
{
  const int b = blockIdx.x;            // 0..4095
  const int t = threadIdx.x;
  const float4* si = (const float4*)(xi + (size_t)b * DIM);
  const float4* sj = (const float4*)(xj + (size_t)b * DIM);
  float4 a0 = si[t * 2], a1 = si[t * 2 + 1];
  float4 c0 = sj[t * 2], c1 = sj[t * 2 + 1];
  float ssi = a0.x*a0.x + a0.y*a0.y + a0.z*a0.z + a0.w*a0.w
            + a1.x*a1.x + a1.y*a1.y + a1.z*a1.z + a1.w*a1.w;
  float ssj = c0.x*c0.x + c0.y*c0.y + c0.z*c0.z + c0.w*c0.w
            + c1.x*c1.x + c1.y*c1.y + c1.z*c1.z + c1.w*c1.w;
  #pragma unroll
  for (int m = 1; m < 64; m <<= 1) {
    ssi += __shfl_xor(ssi, m, 64);
    ssj += __shfl_xor(ssj, m, 64);
  }
  __shared__ float ri[4], rj[4];
  if ((t & 63) == 0) { ri[t >> 6] = ssi; rj[t >> 6] = ssj; }
  __syncthreads();
  float sci = 1.0f / fmaxf(sqrtf(ri[0] + ri[1] + ri[2] + ri[3]), 1e-12f);
  float scj = 1.0f / fmaxf(sqrtf(rj[0] + rj[1] + rj[2] + rj[3]), 1e-12f);

  float fi[8] = {a0.x, a0.y, a0.z, a0.w, a1.x, a1.y, a1.z, a1.w};
  float fj[8] = {c0.x, c0.y, c0.z, c0.w, c1.x, c1.y, c1.z, c1.w};
  float ni[8], nj[8];
  float dp = 0.f;
  #pragma unroll
  for (int e = 0; e < 8; ++e) {
    ni[e] = fi[e] * sci;
    nj[e] = fj[e] * scj;
    dp += ni[e] * nj[e];                 // fp32 positive-pair sim
  }
  // pack 8 scaled values to fp8 (2 words per row-half)
  int wi0 = 0, wi1 = 0, wj0 = 0, wj1 = 0;
  wi0 = __builtin_amdgcn_cvt_pk_fp8_f32(ni[0]*QSCL, ni[1]*QSCL, wi0, false);
  wi0 = __builtin_amdgcn_cvt_pk_fp8_f32(ni[2]*QSCL, ni[3]*QSCL, wi0, true);
  wi1 = __builtin_amdgcn_cvt_pk_fp8_f32(ni[4]*QSCL, ni[5]*QSCL, wi1, false);
  wi1 = __builtin_amdgcn_cvt_pk_fp8_f32(ni[6]*QSCL, ni[7]*QSCL, wi1, true);
  wj0 = __builtin_amdgcn_cvt_pk_fp8_f32(nj[0]*QSCL, nj[1]*QSCL, wj0, false);
  wj0 = __builtin_amdgcn_cvt_pk_fp8_f32(nj[2]*QSCL, nj[3]*QSCL, wj0, true);
  wj1 = __builtin_amdgcn_cvt_pk_fp8_f32(nj[4]*QSCL, nj[5]*QSCL, wj1, false);
  wj1 = __builtin_amdgcn_cvt_pk_fp8_f32(nj[6]*QSCL, nj[7]*QSCL, wj1, true);
  ((int2*)(zq + (size_t)b * ROWB))[t]            = make_int2(wi0, wi1);
  ((int2*)(zq + (size_t)(b + N_HALF) * ROWB))[t] = make_int2(wj0, wj1);

  // self-dots from decoded fp8 (raw, scale 4096) — literal lane selectors
  float dsi = 0.f, dsj = 0.f;
  {
    float d;
    d = __builtin_amdgcn_cvt_f32_fp8(wi0, 0); dsi += d * d;
    d = __builtin_amdgcn_cvt_f32_fp8(wi0, 1); dsi += d * d;
    d = __builtin_amdgcn_cvt_f32_fp8(wi0, 2); dsi += d * d;
    d = __builtin_amdgcn_cvt_f32_fp8(wi0, 3); dsi += d * d;
    d = __builtin_amdgcn_cvt_f32_fp8(wi1, 0); dsi += d * d;
    d = __builtin_amdgcn_cvt_f32_fp8(wi1, 1); dsi += d * d;
    d = __builtin_amdgcn_cvt_f32_fp8(wi1, 2); dsi += d * d;
    d = __builtin_amdgcn_cvt_f32_fp8(wi1, 3); dsi += d * d;
    d = __builtin_amdgcn_cvt_f32_fp8(wj0, 0); dsj += d * d;
    d = __builtin_amdgcn_cvt_f32_fp8(wj0, 1); dsj += d * d;
    d = __builtin_amdgcn_cvt_f32_fp8(wj0, 2); dsj += d * d;
    d = __builtin_amdgcn_cvt_f32_fp8(wj0, 3); dsj += d * d;
    d = __builtin_amdgcn_cvt_f32_fp8(wj1, 0); dsj += d * d;
    d = __builtin_amdgcn_cvt_f32_fp8(wj1, 1); dsj += d * d;
    d = __builtin_amdgcn_cvt_f32_fp8(wj1, 2); dsj += d * d;
    d = __builtin_amdgcn_cvt_f32_fp8(wj1, 3); dsj += d * d;
  }
  #pragma unroll
  for (int m = 1; m < 64; m <<= 1) {
    dp  += __shfl_xor(dp, m, 64);
    dsi += __shfl_xor(dsi, m, 64);
    dsj += __shfl_xor(dsj, m, 64);
  }
  __shared__ float rp[4], rsi[4], rsj[4];
  if ((t & 63) == 0) { rp[t >> 6] = dp; rsi[t >> 6] = dsi; rsj[t >> 6] = dsj; }
  __syncthreads();
  if (t == 0) {
    float p = rp[0] + rp[1] + rp[2] + rp[3];
    pos[b]            = p;
    pos[b + N_HALF]   = p;
    selfd[b]          = rsi[0] + rsi[1] + rsi[2] + rsi[3];
    selfd[b + N_HALF] = rsj[0] + rsj[1] + rsj[2] + rsj[3];
    denom[b]          = 0.f;
    denom[b + N_HALF] = 0.f;
  }
}

// ---------------------------------------------------------------------------
// Kernel 2: fp8 symmetric fused sim-tile + exp row/col sums — r9 STRUCTURE
// (unified grid: 1024 full 256x128 tiles = 2 clean rounds at 2 blk/CU +
// 256 M-split tail blocks), operands fp8 e4m3 via mfma_f32_16x16x32_fp8_fp8.
// 8 waves (4M x 2N), per-wave 64x64 (acc[4][4], 16 MFMA/phase, b64 reads).
// 3-slot LDS rotation lead-2: A-slot 8 KiB (256r x 32B), B-slot 4 KiB
// (128r x 32B) = 36 KiB.  STAGE: A 1 call (all waves), B 1 call (waves 0-3)
// -> per-wave loads 2/1; steady vmcnt(2)/(1); vmcnt(0) final phase.
// LDS layout (both sides, linear gload dest): LDS row q (128 B) = tile rows
// 4q..4q+3; 16B slot s = (g*2 + h) ^ (q&7), g=row-in-group, h=16B-half.
// Bank-audited: ds_read_b64 fragment reads <=2-way (free).
// ---------------------------------------------------------------------------
__global__ __launch_bounds__(512, 4) void simexp_k(
    const char* __restrict__ zq, float* __restrict__ denom)
{
  __shared__ char lds[36864];
  char* ldsA = lds;            // 3 x 8192
  char* ldsB = lds + 24576;    // 3 x 4096

  const int t    = threadIdx.x;
  const int wave = t >> 6, lane = t & 63;
  const int o    = lane >> 4;          // k-octet 0..3
  const int bid  = blockIdx.x;

  // staging-source decomposition (inverse of linear LDS dest):
  // thread t writes LDS row q=t>>3, slot s=t&7 -> logical s0 = s^(q&7):
  const int sqq = t >> 3;
  const int s0  = (t & 7) ^ (sqq & 7);
  const int sg  = s0 >> 1, sh = s0 & 1;

  if (bid < NG1) {
    // ===================== FULL 256x128 TILE PATH ========================
    const int wr = wave >> 1, wc = wave & 1;   // 4M x 2N

    int rem = (bid & 7) * (NG1 / 8) + (bid >> 3);   // XCD-bijective
    int bi = 0;
    while (rem >= 63 - 2 * bi) { rem -= 63 - 2 * bi; ++bi; }
    const int bj   = 2 * bi + rem;               // in [2bi, 63)
    const int row0 = bi * 256;
    const int col0 = bj * 128;

    const char* srcA = zq + (size_t)(row0 + 4 * sqq + sg) * ROWB + sh * 16;
    const char* srcB = zq + (size_t)(col0 + 4 * sqq + sg) * ROWB + sh * 16;
    char* dA = ldsA + wave * 1024;
    char* dB = ldsB + wave * 1024;   // waves 0-3 only

    int offA[4], offB[4];
    #pragma unroll
    for (int m = 0; m < 4; ++m) {
      int r = wr * 64 + m * 16 + (lane & 15);
      int q = r >> 2, g = r & 3;
      offA[m] = q * 128 + (((g * 2 + (o >> 1)) ^ (q & 7)) << 4) + (o & 1) * 8;
    }
    #pragma unroll
    for (int n = 0; n < 4; ++n) {
      int r = wc * 64 + n * 16 + (lane & 15);
      int q = r >> 2, g = r & 3;
      offB[n] = q * 128 + (((g * 2 + (o >> 1)) ^ (q & 7)) << 4) + (o & 1) * 8;
    }

    f32x4 acc[4][4] = {};

#define STAGE(kt, slot) do {                                   \
      gload_lds16(srcA + (kt) * 32, dA + (slot) * 8192);       \
      if (wave < 4)                                            \
        gload_lds16(srcB + (kt) * 32, dB + (slot) * 4096);     \
    } while (0)

    STAGE(0, 0);
    STAGE(1, 1);

    int sl = 0;
    for (int p = 0; p < NPH; ++p) {
      if (p < NPH - 1) {
        if (wave < 4) asm volatile("s_waitcnt vmcnt(2)" ::: "memory");
        else          asm volatile("s_waitcnt vmcnt(1)" ::: "memory");
      } else {
        asm volatile("s_waitcnt vmcnt(0)" ::: "memory");
      }
      __builtin_amdgcn_s_barrier();
      __builtin_amdgcn_sched_barrier(0);

      const char* Ab = ldsA + sl * 8192;
      const char* Bb = ldsB + sl * 4096;
      long a[4], b[4];
      #pragma unroll
      for (int m = 0; m < 4; ++m) a[m] = *(const long*)(Ab + offA[m]);
      #pragma unroll
      for (int n = 0; n < 4; ++n) b[n] = *(const long*)(Bb + offB[n]);

      if (p + 2 < NPH) {
        int s2 = sl + 2; if (s2 >= 3) s2 -= 3;
        STAGE(p + 2, s2);
      }

      __builtin_amdgcn_s_setprio(1);
      #pragma unroll
      for (int m = 0; m < 4; ++m)
        #pragma unroll
        for (int n = 0; n < 4; ++n)
          acc[m][n] = __builtin_amdgcn_mfma_f32_16x16x32_fp8_fp8(
              a[m], b[n], acc[m][n], 0, 0, 0);
      __builtin_amdgcn_s_setprio(0);
      __builtin_amdgcn_sched_barrier(0);

      if (++sl >= 3) sl = 0;
    }
#undef STAGE

    #pragma unroll
    for (int m = 0; m < 4; ++m)
      #pragma unroll
      for (int n = 0; n < 4; ++n)
        #pragma unroll
        for (int r = 0; r < 4; ++r)
          acc[m][n][r] = __expf(acc[m][n][r] * SIMSCL);

    // row sums: C layout col = lane&15, row = (lane>>4)*4 + reg
    #pragma unroll
    for (int m = 0; m < 4; ++m) {
      #pragma unroll
      for (int r = 0; r < 4; ++r) {
        float s = acc[m][0][r] + acc[m][1][r] + acc[m][2][r] + acc[m][3][r];
        s += __shfl_xor(s, 1, 64);
        s += __shfl_xor(s, 2, 64);
        s += __shfl_xor(s, 4, 64);
        s += __shfl_xor(s, 8, 64);
        if ((lane & 15) == 0) {
          int grow = row0 + wr * 64 + m * 16 + (lane >> 4) * 4 + r;
          atomicAdd(&denom[grow], s);
        }
      }
    }

    if (bj >= 2 * bi + 2) {
      #pragma unroll
      for (int n = 0; n < 4; ++n) {
        float cs = 0.f;
        #pragma unroll
        for (int m = 0; m < 4; ++m)
          #pragma unroll
          for (int r = 0; r < 4; ++r)
            cs += acc[m][n][r];
        cs += __shfl_xor(cs, 16, 64);
        cs += __shfl_xor(cs, 32, 64);
        if ((lane >> 4) == 0) {
          int gcol = col0 + wc * 64 + n * 16 + (lane & 15);
          atomicAdd(&denom[gcol], cs);
        }
      }
    }
  } else {
    // ===================== TAIL PATH: 32-row x 128-col, cols 8064 ========
    const int sub  = bid - NG1;                // 0..255
    const int bi   = sub >> 3;                 // band 0..31
    const int row0 = bi * 256 + (sub & 7) * 32;
    const int col0 = 8064;

    const char* srcB  = zq + (size_t)(col0 + 4 * sqq + sg) * ROWB + sh * 16;
    // A: 1 KiB staged by wave 0 (t<64): q = t>>3 in 0..7 -> rows 0..31
    const char* srcAs = zq + (size_t)(row0 + 4 * sqq + sg) * ROWB + sh * 16;

    int offA2[2], offB0;
    #pragma unroll
    for (int m = 0; m < 2; ++m) {
      int r = m * 16 + (lane & 15);            // 0..31
      int q = r >> 2, g = r & 3;
      offA2[m] = q * 128 + (((g * 2 + (o >> 1)) ^ (q & 7)) << 4) + (o & 1) * 8;
    }
    {
      int r = wave * 16 + (lane & 15);         // 0..127
      int q = r >> 2, g = r & 3;
      offB0 = q * 128 + (((g * 2 + (o >> 1)) ^ (q & 7)) << 4) + (o & 1) * 8;
    }

    f32x4 acc2[2] = {};

#define STAGE_T(kt, slot) do {                                            \
      if (wave < 4)                                                       \
        gload_lds16(srcB + (kt) * 32, ldsB + (slot) * 4096 + wave * 1024);\
      if (wave == 0)                                                      \
        gload_lds16(srcAs + (kt) * 32, ldsA + (slot) * 8192);             \
    } while (0)

    STAGE_T(0, 0);
    STAGE_T(1, 1);

    int sl = 0;
    for (int p = 0; p < NPH; ++p) {
      if (p < NPH - 1) {
        if (wave == 0)     asm volatile("s_waitcnt vmcnt(2)" ::: "memory");
        else if (wave < 4) asm volatile("s_waitcnt vmcnt(1)" ::: "memory");
        else               asm volatile("s_waitcnt vmcnt(0)" ::: "memory");
      } else {
        asm volatile("s_waitcnt vmcnt(0)" ::: "memory");
      }
      __builtin_amdgcn_s_barrier();
      __builtin_amdgcn_sched_barrier(0);

      const char* Ab = ldsA + sl * 8192;
      const char* Bb = ldsB + sl * 4096;
      long a0 = *(const long*)(Ab + offA2[0]);
      long a1 = *(const long*)(Ab + offA2[1]);
      long b0 = *(const long*)(Bb + offB0);

      if (p + 2 < NPH) {
        int s2 = sl + 2; if (s2 >= 3) s2 -= 3;
        STAGE_T(p + 2, s2);
      }

      __builtin_amdgcn_s_setprio(1);
      acc2[0] = __builtin_amdgcn_mfma_f32_16x16x32_fp8_fp8(a0, b0, acc2[0], 0, 0, 0);
      acc2[1] = __builtin_amdgcn_mfma_f32_16x16x32_fp8_fp8(a1, b0, acc2[1], 0, 0, 0);
      __builtin_amdgcn_s_setprio(0);
      __builtin_amdgcn_sched_barrier(0);

      if (++sl >= 3) sl = 0;
    }
#undef STAGE_T

    #pragma unroll
    for (int m = 0; m < 2; ++m)
      #pragma unroll
      for (int r = 0; r < 4; ++r)
        acc2[m][r] = __expf(acc2[m][r] * SIMSCL);

    // row sums (16 cols per wave slice, atomic-accumulated)
    #pragma unroll
    for (int m = 0; m < 2; ++m) {
      #pragma unroll
      for (int r = 0; r < 4; ++r) {
        float s = acc2[m][r];
        s += __shfl_xor(s, 1, 64);
        s += __shfl_xor(s, 2, 64);
        s += __shfl_xor(s, 4, 64);
        s += __shfl_xor(s, 8, 64);
        if ((lane & 15) == 0) {
          int grow = row0 + m * 16 + (lane >> 4) * 4 + r;
          atomicAdd(&denom[grow], s);
        }
      }
    }

    // col sums — strip right of band diag for bi <= 30
    if (bi <= 30) {
      float cs = 0.f;
      #pragma unroll
      for (int m = 0; m < 2; ++m)
        #pragma unroll
        for (int r = 0; r < 4; ++r)
          cs += acc2[m][r];
      cs += __shfl_xor(cs, 16, 64);
      cs += __shfl_xor(cs, 32, 64);
      if ((lane >> 4) == 0) {
        int gcol = col0 + wave * 16 + (lane & 15);
        atomicAdd(&denom[gcol], cs);
      }
    }
  }
}

// ---------------------------------------------------------------------------
// Kernel 3: loss = mean_i( log(denom_i - exp(self_i*SIMSCL)) - pos_i*INV_T )
// ---------------------------------------------------------------------------
__global__ __launch_bounds__(256) void loss_k(
    const float* __restrict__ denom, const float* __restrict__ pos,
    const float* __restrict__ selfd, float* __restrict__ out)
{
  const int t = threadIdx.x;
  float acc = 0.f;
  for (int i = t; i < N_ROWS; i += 256) {
    float d = denom[i] - __expf(selfd[i] * SIMSCL);
    acc += __logf(d) - pos[i] * INV_T;
  }
  #pragma unroll
  for (int m = 1; m < 64; m <<= 1) acc += __shfl_xor(acc, m, 64);
  __shared__ float red[4];
  if ((t & 63) == 0) red[t >> 6] = acc;
  __syncthreads();
  if (t == 0) out[0] = (red[0] + red[1] + red[2] + red[3]) / (float)N_ROWS;
}

// ---------------------------------------------------------------------------
extern "C" void kernel_launch(void* const* d_in, const int* in_sizes, int n_in,
                              void* d_out, int out_size, void* d_ws, size_t ws_size,
                              hipStream_t stream) {
  const float* xi = (const float*)d_in[0];
  const float* xj = (const float*)d_in[1];
  float* out = (float*)d_out;

  char*  ws    = (char*)d_ws;
  char*  zq    = ws;                                           // 16 MiB fp8 z
  float* denom = (float*)(ws + (size_t)N_ROWS * ROWB);         // 8192 f32
  float* pos   = denom + N_ROWS;
  float* selfd = pos + N_ROWS;

  normpos_k<<<N_HALF, 256, 0, stream>>>(xi, xj, zq, pos, selfd, denom);
  simexp_k<<<NG1 + NG2, 512, 0, stream>>>(zq, denom);
  loss_k<<<1, 256, 0, stream>>>(denom, pos, selfd, out);
}

// Round 17
// 124.821 us; speedup vs baseline: 1.6057x; 1.2062x over previous
//
#include <hip/hip_runtime.h>
#include <hip/hip_bf16.h>

#define N_ROWS 8192
#define N_HALF 4096
#define DIM    2048
#define ROWB   2048       // bytes per z row (fp8)
#define INV_T  2.0f
#define QSCL   64.0f      // z scaled by 64 before fp8 quant
#define SIMSCL 0.00048828125f  // INV_T / (QSCL*QSCL) = 2/4096
#define NG1    1024       // full tiles: sum_{bi}(63-2*bi), bj in [2bi,63)
#define NG2    256        // tail: 32 bj=63 tiles M-split x8
#define NKT    32         // DIM/64 K-tiles

typedef __attribute__((ext_vector_type(4))) float f32x4;
typedef __attribute__((ext_vector_type(2))) long lx2;

__device__ __forceinline__ void gload_lds16(const void* g, void* l) {
  __builtin_amdgcn_global_load_lds(
      (const __attribute__((address_space(1))) unsigned int*)g,
      (__attribute__((address_space(3))) unsigned int*)l, 16, 0, 0);
}

// ---------------------------------------------------------------------------
// Kernel 1: fused normalize + fp8-quantize + positives + self-dots + denom=0.
// zq is stored K-INTERLEAVED: within each 64-k group, element k sits at byte
//   (k>>6)*64 + ((k>>3)&3)*16 + ((k>>5)&1)*8 + (k&7)
// so a 16B chunk at o*16 holds octet o of K-step0 (8B) then K-step1 (8B).
// Thread t owns k = 8t..8t+7 (one octet): pos = (t>>3)*64 + (t&3)*16 +
// ((t>>2)&1)*8.
// ---------------------------------------------------------------------------
__global__ __launch_bounds__(256) void normpos_k(
    const float* __restrict__ xi, const float* __restrict__ xj,
    char* __restrict__ zq, float* __restrict__ pos,
    float* __restrict__ selfd, float* __restrict__ denom)
{
  const int b = blockIdx.x;            // 0..4095
  const int t = threadIdx.x;
  const float4* si = (const float4*)(xi + (size_t)b * DIM);
  const float4* sj = (const float4*)(xj + (size_t)b * DIM);
  float4 a0 = si[t * 2], a1 = si[t * 2 + 1];
  float4 c0 = sj[t * 2], c1 = sj[t * 2 + 1];
  float ssi = a0.x*a0.x + a0.y*a0.y + a0.z*a0.z + a0.w*a0.w
            + a1.x*a1.x + a1.y*a1.y + a1.z*a1.z + a1.w*a1.w;
  float ssj = c0.x*c0.x + c0.y*c0.y + c0.z*c0.z + c0.w*c0.w
            + c1.x*c1.x + c1.y*c1.y + c1.z*c1.z + c1.w*c1.w;
  #pragma unroll
  for (int m = 1; m < 64; m <<= 1) {
    ssi += __shfl_xor(ssi, m, 64);
    ssj += __shfl_xor(ssj, m, 64);
  }
  __shared__ float ri[4], rj[4];
  if ((t & 63) == 0) { ri[t >> 6] = ssi; rj[t >> 6] = ssj; }
  __syncthreads();
  float sci = 1.0f / fmaxf(sqrtf(ri[0] + ri[1] + ri[2] + ri[3]), 1e-12f);
  float scj = 1.0f / fmaxf(sqrtf(rj[0] + rj[1] + rj[2] + rj[3]), 1e-12f);

  float fi[8] = {a0.x, a0.y, a0.z, a0.w, a1.x, a1.y, a1.z, a1.w};
  float fj[8] = {c0.x, c0.y, c0.z, c0.w, c1.x, c1.y, c1.z, c1.w};
  float ni[8], nj[8];
  float dp = 0.f;
  #pragma unroll
  for (int e = 0; e < 8; ++e) {
    ni[e] = fi[e] * sci;
    nj[e] = fj[e] * scj;
    dp += ni[e] * nj[e];                 // fp32 positive-pair sim
  }
  int wi0 = 0, wi1 = 0, wj0 = 0, wj1 = 0;
  wi0 = __builtin_amdgcn_cvt_pk_fp8_f32(ni[0]*QSCL, ni[1]*QSCL, wi0, false);
  wi0 = __builtin_amdgcn_cvt_pk_fp8_f32(ni[2]*QSCL, ni[3]*QSCL, wi0, true);
  wi1 = __builtin_amdgcn_cvt_pk_fp8_f32(ni[4]*QSCL, ni[5]*QSCL, wi1, false);
  wi1 = __builtin_amdgcn_cvt_pk_fp8_f32(ni[6]*QSCL, ni[7]*QSCL, wi1, true);
  wj0 = __builtin_amdgcn_cvt_pk_fp8_f32(nj[0]*QSCL, nj[1]*QSCL, wj0, false);
  wj0 = __builtin_amdgcn_cvt_pk_fp8_f32(nj[2]*QSCL, nj[3]*QSCL, wj0, true);
  wj1 = __builtin_amdgcn_cvt_pk_fp8_f32(nj[4]*QSCL, nj[5]*QSCL, wj1, false);
  wj1 = __builtin_amdgcn_cvt_pk_fp8_f32(nj[6]*QSCL, nj[7]*QSCL, wj1, true);

  const size_t ipos = (size_t)(t >> 3) * 64 + (t & 3) * 16 + ((t >> 2) & 1) * 8;
  *(int2*)(zq + (size_t)b * ROWB + ipos)            = make_int2(wi0, wi1);
  *(int2*)(zq + (size_t)(b + N_HALF) * ROWB + ipos) = make_int2(wj0, wj1);

  // self-dots from decoded fp8 (raw, scale 4096) — literal lane selectors
  float dsi = 0.f, dsj = 0.f;
  {
    float d;
    d = __builtin_amdgcn_cvt_f32_fp8(wi0, 0); dsi += d * d;
    d = __builtin_amdgcn_cvt_f32_fp8(wi0, 1); dsi += d * d;
    d = __builtin_amdgcn_cvt_f32_fp8(wi0, 2); dsi += d * d;
    d = __builtin_amdgcn_cvt_f32_fp8(wi0, 3); dsi += d * d;
    d = __builtin_amdgcn_cvt_f32_fp8(wi1, 0); dsi += d * d;
    d = __builtin_amdgcn_cvt_f32_fp8(wi1, 1); dsi += d * d;
    d = __builtin_amdgcn_cvt_f32_fp8(wi1, 2); dsi += d * d;
    d = __builtin_amdgcn_cvt_f32_fp8(wi1, 3); dsi += d * d;
    d = __builtin_amdgcn_cvt_f32_fp8(wj0, 0); dsj += d * d;
    d = __builtin_amdgcn_cvt_f32_fp8(wj0, 1); dsj += d * d;
    d = __builtin_amdgcn_cvt_f32_fp8(wj0, 2); dsj += d * d;
    d = __builtin_amdgcn_cvt_f32_fp8(wj0, 3); dsj += d * d;
    d = __builtin_amdgcn_cvt_f32_fp8(wj1, 0); dsj += d * d;
    d = __builtin_amdgcn_cvt_f32_fp8(wj1, 1); dsj += d * d;
    d = __builtin_amdgcn_cvt_f32_fp8(wj1, 2); dsj += d * d;
    d = __builtin_amdgcn_cvt_f32_fp8(wj1, 3); dsj += d * d;
  }
  #pragma unroll
  for (int m = 1; m < 64; m <<= 1) {
    dp  += __shfl_xor(dp, m, 64);
    dsi += __shfl_xor(dsi, m, 64);
    dsj += __shfl_xor(dsj, m, 64);
  }
  __shared__ float rp[4], rsi[4], rsj[4];
  if ((t & 63) == 0) { rp[t >> 6] = dp; rsi[t >> 6] = dsi; rsj[t >> 6] = dsj; }
  __syncthreads();
  if (t == 0) {
    float p = rp[0] + rp[1] + rp[2] + rp[3];
    pos[b]            = p;
    pos[b + N_HALF]   = p;
    selfd[b]          = rsi[0] + rsi[1] + rsi[2] + rsi[3];
    selfd[b + N_HALF] = rsj[0] + rsj[1] + rsj[2] + rsj[3];
    denom[b]          = 0.f;
    denom[b + N_HALF] = 0.f;
  }
}

// ---------------------------------------------------------------------------
// Kernel 2: fp8 symmetric fused sim-tile + exp row/col sums, BK=64.
// Grid: 1024 full 256x128 tiles (2 clean rounds) + 256 M-split tail blocks.
// 8 waves (4M x 2N), per-wave 64x64; per K-tile(64): 4 A + 4 B ds_read_b128
// (each delivers BOTH K-steps' octets via the interleaved layout) feeding
// 32 MFMAs (16x16x32 fp8).  Bank-conflict-free: a 16-lane phase covers 8
// distinct 16B slots x 2 rows = all 32 banks over the inherent 2 clocks.
// LDS: 3-slot rotation lead-2; A-slot 16 KiB (LDS row q=128B holds tile
// rows 2q,2q+1; 16B slot s0=(rr*4+o)^(q&7)), B-slot 8 KiB.  STAGE = 3
// uniform gload_lds16 calls/wave -> steady vmcnt(3), final vmcnt(0).
// Staged via inverse-swizzled global source (zq pre-interleaved), linear
// LDS dest.
// ---------------------------------------------------------------------------
__global__ __launch_bounds__(512, 4) void simexp_k(
    const char* __restrict__ zq, float* __restrict__ denom)
{
  __shared__ char lds[73728];
  char* ldsA = lds;            // 3 x 16384 (tail: 3 x 2048)
  char* ldsB = lds + 49152;    // 3 x 8192

  const int t    = threadIdx.x;
  const int wave = t >> 6, lane = t & 63;
  const int o    = lane >> 4;          // k-octet 0..3
  const int bid  = blockIdx.x;

  // staging-source decomposition (inverse of linear LDS dest):
  // thread t -> LDS row q=t>>3, slot s=t&7; logical s0 = s^(q&7):
  const int sqq = t >> 3;              // 0..63
  const int s0  = (t & 7) ^ (sqq & 7);
  const int srr = s0 >> 2;             // row parity
  const int so  = s0 & 3;              // octet-pair index

  if (bid < NG1) {
    // ===================== FULL 256x128 TILE PATH ========================
    const int wr = wave >> 1, wc = wave & 1;   // 4M x 2N

    int rem = (bid & 7) * (NG1 / 8) + (bid >> 3);   // XCD-bijective
    int bi = 0;
    while (rem >= 63 - 2 * bi) { rem -= 63 - 2 * bi; ++bi; }
    const int bj   = 2 * bi + rem;               // in [2bi, 63)
    const int row0 = bi * 256;
    const int col0 = bj * 128;

    const char* srcA0 = zq + (size_t)(row0 + 2 * sqq + srr) * ROWB + so * 16;
    const char* srcA1 = srcA0 + (size_t)128 * ROWB;
    const char* srcB  = zq + (size_t)(col0 + 2 * sqq + srr) * ROWB + so * 16;
    char* dA = ldsA + wave * 1024;
    char* dB = ldsB + wave * 1024;

    int offA[4], offB[4];
    #pragma unroll
    for (int m = 0; m < 4; ++m) {
      int r = wr * 64 + m * 16 + (lane & 15);
      int q = r >> 1;
      offA[m] = q * 128 + ((((r & 1) * 4 + o) ^ (q & 7)) << 4);
    }
    #pragma unroll
    for (int n = 0; n < 4; ++n) {
      int r = wc * 64 + n * 16 + (lane & 15);
      int q = r >> 1;
      offB[n] = q * 128 + ((((r & 1) * 4 + o) ^ (q & 7)) << 4);
    }

    f32x4 acc[4][4] = {};

#define STAGE(kt, slot) do {                                   \
      gload_lds16(srcA0 + (kt) * 64, dA + (slot) * 16384);     \
      gload_lds16(srcA1 + (kt) * 64, dA + (slot) * 16384 + 8192); \
      gload_lds16(srcB  + (kt) * 64, dB + (slot) * 8192);      \
    } while (0)

    STAGE(0, 0);
    STAGE(1, 1);

    int sl = 0;
    for (int p = 0; p < NKT; ++p) {
      if (p < NKT - 1) asm volatile("s_waitcnt vmcnt(3)" ::: "memory");
      else             asm volatile("s_waitcnt vmcnt(0)" ::: "memory");
      __builtin_amdgcn_s_barrier();
      __builtin_amdgcn_sched_barrier(0);

      const char* Ab = ldsA + sl * 16384;
      const char* Bb = ldsB + sl * 8192;
      lx2 a[4], b[4];
      #pragma unroll
      for (int m = 0; m < 4; ++m) a[m] = *(const lx2*)(Ab + offA[m]);
      #pragma unroll
      for (int n = 0; n < 4; ++n) b[n] = *(const lx2*)(Bb + offB[n]);

      if (p + 2 < NKT) {
        int s2 = sl + 2; if (s2 >= 3) s2 -= 3;
        STAGE(p + 2, s2);
      }

      __builtin_amdgcn_s_setprio(1);
      #pragma unroll
      for (int m = 0; m < 4; ++m)
        #pragma unroll
        for (int n = 0; n < 4; ++n)
          acc[m][n] = __builtin_amdgcn_mfma_f32_16x16x32_fp8_fp8(
              a[m][0], b[n][0], acc[m][n], 0, 0, 0);
      #pragma unroll
      for (int m = 0; m < 4; ++m)
        #pragma unroll
        for (int n = 0; n < 4; ++n)
          acc[m][n] = __builtin_amdgcn_mfma_f32_16x16x32_fp8_fp8(
              a[m][1], b[n][1], acc[m][n], 0, 0, 0);
      __builtin_amdgcn_s_setprio(0);
      __builtin_amdgcn_sched_barrier(0);

      if (++sl >= 3) sl = 0;
    }
#undef STAGE

    #pragma unroll
    for (int m = 0; m < 4; ++m)
      #pragma unroll
      for (int n = 0; n < 4; ++n)
        #pragma unroll
        for (int r = 0; r < 4; ++r)
          acc[m][n][r] = __expf(acc[m][n][r] * SIMSCL);

    // row sums: C layout col = lane&15, row = (lane>>4)*4 + reg
    #pragma unroll
    for (int m = 0; m < 4; ++m) {
      #pragma unroll
      for (int r = 0; r < 4; ++r) {
        float s = acc[m][0][r] + acc[m][1][r] + acc[m][2][r] + acc[m][3][r];
        s += __shfl_xor(s, 1, 64);
        s += __shfl_xor(s, 2, 64);
        s += __shfl_xor(s, 4, 64);
        s += __shfl_xor(s, 8, 64);
        if ((lane & 15) == 0) {
          int grow = row0 + wr * 64 + m * 16 + (lane >> 4) * 4 + r;
          atomicAdd(&denom[grow], s);
        }
      }
    }

    if (bj >= 2 * bi + 2) {
      #pragma unroll
      for (int n = 0; n < 4; ++n) {
        float cs = 0.f;
        #pragma unroll
        for (int m = 0; m < 4; ++m)
          #pragma unroll
          for (int r = 0; r < 4; ++r)
            cs += acc[m][n][r];
        cs += __shfl_xor(cs, 16, 64);
        cs += __shfl_xor(cs, 32, 64);
        if ((lane >> 4) == 0) {
          int gcol = col0 + wc * 64 + n * 16 + (lane & 15);
          atomicAdd(&denom[gcol], cs);
        }
      }
    }
  } else {
    // ===================== TAIL PATH: 32-row x 128-col, cols 8064 ========
    const int sub  = bid - NG1;                // 0..255
    const int bi   = sub >> 3;                 // band 0..31
    const int row0 = bi * 256 + (sub & 7) * 32;
    const int col0 = 8064;

    const char* srcB = zq + (size_t)(col0 + 2 * sqq + srr) * ROWB + so * 16;
    // A: 2 KiB staged by waves 0-1 (t<128): q = (t&127)>>3 in 0..15
    const int tA   = t & 127;
    const int sqA  = tA >> 3;
    const int s0A  = (tA & 7) ^ (sqA & 7);
    const char* srcAs = zq + (size_t)(row0 + 2 * sqA + (s0A >> 2)) * ROWB
                      + (s0A & 3) * 16;

    int offA2[2], offB0;
    #pragma unroll
    for (int m = 0; m < 2; ++m) {
      int r = m * 16 + (lane & 15);            // 0..31
      int q = r >> 1;
      offA2[m] = q * 128 + ((((r & 1) * 4 + o) ^ (q & 7)) << 4);
    }
    {
      int r = wave * 16 + (lane & 15);         // 0..127
      int q = r >> 1;
      offB0 = q * 128 + ((((r & 1) * 4 + o) ^ (q & 7)) << 4);
    }

    f32x4 acc2[2] = {};

#define STAGE_T(kt, slot) do {                                            \
      gload_lds16(srcB + (kt) * 64, ldsB + (slot) * 8192 + wave * 1024);  \
      if (wave < 2)                                                       \
        gload_lds16(srcAs + (kt) * 64,                                    \
                    ldsA + (slot) * 2048 + wave * 1024);                  \
    } while (0)

    STAGE_T(0, 0);
    STAGE_T(1, 1);

    int sl = 0;
    for (int p = 0; p < NKT; ++p) {
      if (p < NKT - 1) {
        if (wave < 2) asm volatile("s_waitcnt vmcnt(2)" ::: "memory");
        else          asm volatile("s_waitcnt vmcnt(1)" ::: "memory");
      } else {
        asm volatile("s_waitcnt vmcnt(0)" ::: "memory");
      }
      __builtin_amdgcn_s_barrier();
      __builtin_amdgcn_sched_barrier(0);

      const char* Ab = ldsA + sl * 2048;
      const char* Bb = ldsB + sl * 8192;
      lx2 a0 = *(const lx2*)(Ab + offA2[0]);
      lx2 a1 = *(const lx2*)(Ab + offA2[1]);
      lx2 b0 = *(const lx2*)(Bb + offB0);

      if (p + 2 < NKT) {
        int s2 = sl + 2; if (s2 >= 3) s2 -= 3;
        STAGE_T(p + 2, s2);
      }

      __builtin_amdgcn_s_setprio(1);
      acc2[0] = __builtin_amdgcn_mfma_f32_16x16x32_fp8_fp8(a0[0], b0[0], acc2[0], 0, 0, 0);
      acc2[1] = __builtin_amdgcn_mfma_f32_16x16x32_fp8_fp8(a1[0], b0[0], acc2[1], 0, 0, 0);
      acc2[0] = __builtin_amdgcn_mfma_f32_16x16x32_fp8_fp8(a0[1], b0[1], acc2[0], 0, 0, 0);
      acc2[1] = __builtin_amdgcn_mfma_f32_16x16x32_fp8_fp8(a1[1], b0[1], acc2[1], 0, 0, 0);
      __builtin_amdgcn_s_setprio(0);
      __builtin_amdgcn_sched_barrier(0);

      if (++sl >= 3) sl = 0;
    }
#undef STAGE_T

    #pragma unroll
    for (int m = 0; m < 2; ++m)
      #pragma unroll
      for (int r = 0; r < 4; ++r)
        acc2[m][r] = __expf(acc2[m][r] * SIMSCL);

    // row sums (16 cols per wave slice, atomic-accumulated)
    #pragma unroll
    for (int m = 0; m < 2; ++m) {
      #pragma unroll
      for (int r = 0; r < 4; ++r) {
        float s = acc2[m][r];
        s += __shfl_xor(s, 1, 64);
        s += __shfl_xor(s, 2, 64);
        s += __shfl_xor(s, 4, 64);
        s += __shfl_xor(s, 8, 64);
        if ((lane & 15) == 0) {
          int grow = row0 + m * 16 + (lane >> 4) * 4 + r;
          atomicAdd(&denom[grow], s);
        }
      }
    }

    // col sums — strip right of band diag for bi <= 30
    if (bi <= 30) {
      float cs = 0.f;
      #pragma unroll
      for (int m = 0; m < 2; ++m)
        #pragma unroll
        for (int r = 0; r < 4; ++r)
          cs += acc2[m][r];
      cs += __shfl_xor(cs, 16, 64);
      cs += __shfl_xor(cs, 32, 64);
      if ((lane >> 4) == 0) {
        int gcol = col0 + wave * 16 + (lane & 15);
        atomicAdd(&denom[gcol], cs);
      }
    }
  }
}

// ---------------------------------------------------------------------------
// Kernel 3: loss = mean_i( log(denom_i - exp(self_i*SIMSCL)) - pos_i*INV_T )
// ---------------------------------------------------------------------------
__global__ __launch_bounds__(256) void loss_k(
    const float* __restrict__ denom, const float* __restrict__ pos,
    const float* __restrict__ selfd, float* __restrict__ out)
{
  const int t = threadIdx.x;
  float acc = 0.f;
  for (int i = t; i < N_ROWS; i += 256) {
    float d = denom[i] - __expf(selfd[i] * SIMSCL);
    acc += __logf(d) - pos[i] * INV_T;
  }
  #pragma unroll
  for (int m = 1; m < 64; m <<= 1) acc += __shfl_xor(acc, m, 64);
  __shared__ float red[4];
  if ((t & 63) == 0) red[t >> 6] = acc;
  __syncthreads();
  if (t == 0) out[0] = (red[0] + red[1] + red[2] + red[3]) / (float)N_ROWS;
}

// ---------------------------------------------------------------------------
extern "C" void kernel_launch(void* const* d_in, const int* in_sizes, int n_in,
                              void* d_out, int out_size, void* d_ws, size_t ws_size,
                              hipStream_t stream) {
  const float* xi = (const float*)d_in[0];
  const float* xj = (const float*)d_in[1];
  float* out = (float*)d_out;

  char*  ws    = (char*)d_ws;
  char*  zq    = ws;                                           // 16 MiB fp8 z
  float* denom = (float*)(ws + (size_t)N_ROWS * ROWB);         // 8192 f32
  float* pos   = denom + N_ROWS;
  float* selfd = pos + N_ROWS;

  normpos_k<<<N_HALF, 256, 0, stream>>>(xi, xj, zq, pos, selfd, denom);
  simexp_k<<<NG1 + NG2, 512, 0, stream>>>(zq, denom);
  loss_k<<<1, 256, 0, stream>>>(denom, pos, selfd, out);
}